// Round 1
// baseline (857.353 us; speedup 1.0000x reference)
//
#include <hip/hip_runtime.h>
#include <hip/hip_bf16.h>
#include <stdint.h>

#define B_   8
#define N_   4096
#define K1_  17
#define D_   256
#define NT_  (B_*N_)          // 32768
#define E16_ (NT_*16)         // 524288
#define NP_  (NT_*D_)         // 8388608
#define EPS_ 1e-5f

// ---------------- edge-structure kernels ----------------

__global__ void k_zero(int* __restrict__ degcnt){
  int i = blockIdx.x*blockDim.x + threadIdx.x;
  if (i < NT_) degcnt[i] = 0;
}

// Detect edge_mask storage: 0 = int32 {0,1}, 1 = float32 {0.f,1.f}, 2 = uint8/bool
__global__ void k_detect(const unsigned int* __restrict__ mw, int* __restrict__ flag){
  if (threadIdx.x==0 && blockIdx.x==0){
    int isInt=1, isF32=1;
    for (int i=0;i<1024;i++){
      unsigned w = mw[i];
      if (!(w==0u || w==1u)) isInt=0;
      if (!(w==0u || w==0x3F800000u)) isF32=0;
    }
    *flag = isInt ? 0 : (isF32 ? 1 : 2);
  }
}

__device__ __forceinline__ bool mask_at(const void* maskp, int f, int idx){
  if (f==0) return ((const int*)maskp)[idx] != 0;
  if (f==1) return ((const float*)maskp)[idx] != 0.0f;
  return ((const unsigned char*)maskp)[idx] != 0;
}

__global__ void k_deg(const int* __restrict__ knn, const void* __restrict__ maskp,
                      const int* __restrict__ flag, int* __restrict__ degcnt){
  int f = *flag;
  int e = blockIdx.x*blockDim.x + threadIdx.x;
  if (e >= E16_) return;
  int node = e >> 4;            // b*N + n
  int k    = (e & 15) + 1;      // skip k=0
  int idx  = node*K1_ + k;
  if (mask_at(maskp, f, idx)){
    int b   = node >> 12;       // node / N_
    int dst = knn[idx] + (b<<12);
    atomicAdd(&degcnt[dst], 1);
  }
}

// one block of 1024 threads: exclusive scan of degcnt -> rowptr, fillptr, dinv
__global__ void k_scan(const int* __restrict__ degcnt, int* __restrict__ rowptr,
                       int* __restrict__ fillptr, float* __restrict__ dinv){
  __shared__ int sm[1024];
  int t = threadIdx.x;
  int base = t*32;
  int loc[32]; int tot = 0;
  #pragma unroll
  for (int i=0;i<32;i++){ loc[i] = degcnt[base+i]; tot += loc[i]; }
  sm[t] = tot; __syncthreads();
  for (int off=1; off<1024; off<<=1){
    int v = (t>=off) ? sm[t-off] : 0;
    __syncthreads();
    sm[t] += v;
    __syncthreads();
  }
  int run = sm[t] - tot;        // exclusive prefix
  #pragma unroll
  for (int i=0;i<32;i++){
    int v = base+i;
    rowptr[v]  = run;
    fillptr[v] = run;
    dinv[v]    = rsqrtf((float)loc[i] + 1.0f);
    run += loc[i];
  }
  if (t==1023) rowptr[NT_] = run;
}

__global__ void k_fill(const int* __restrict__ knn, const void* __restrict__ maskp,
                       const int* __restrict__ flag, int* __restrict__ fillptr,
                       int* __restrict__ col){
  int f = *flag;
  int e = blockIdx.x*blockDim.x + threadIdx.x;
  if (e >= E16_) return;
  int node = e >> 4;
  int k    = (e & 15) + 1;
  int idx  = node*K1_ + k;
  if (mask_at(maskp, f, idx)){
    int b   = node >> 12;
    int dst = knn[idx] + (b<<12);
    int pos = atomicAdd(&fillptr[dst], 1);
    col[pos] = node;            // src
  }
}

// ---------------- per-layer kernels ----------------

// out[row][c] = sum_k H[row][k] * W[k][c]; 16 rows x 256 cols per block
__global__ __launch_bounds__(256) void k_gemm(const float* __restrict__ H, int ldh,
                                              const float* __restrict__ W,
                                              float* __restrict__ out){
  __shared__ float Ws[32][256];
  __shared__ float Hs[16][32];
  int tid  = threadIdx.x;
  int row0 = blockIdx.x * 16;
  float acc[16];
  #pragma unroll
  for (int r=0;r<16;r++) acc[r]=0.f;

  for (int kc=0; kc<D_; kc+=32){
    #pragma unroll
    for (int i=0;i<32;i++) Ws[i][tid] = W[(kc+i)*D_ + tid];
    {
      int idx = tid;
      Hs[idx>>5][idx&31] = H[(row0 + (idx>>5))*ldh + kc + (idx&31)];
      idx = tid + 256;
      Hs[idx>>5][idx&31] = H[(row0 + (idx>>5))*ldh + kc + (idx&31)];
    }
    __syncthreads();
    #pragma unroll
    for (int k4=0;k4<32;k4+=4){
      float4 h4[16];
      #pragma unroll
      for (int r=0;r<16;r++) h4[r] = *(const float4*)&Hs[r][k4];
      #pragma unroll
      for (int j=0;j<4;j++){
        float wv = Ws[k4+j][tid];
        #pragma unroll
        for (int r=0;r<16;r++){
          float hv = (j==0)?h4[r].x : (j==1)?h4[r].y : (j==2)?h4[r].z : h4[r].w;
          acc[r] += hv*wv;
        }
      }
    }
    __syncthreads();
  }
  #pragma unroll
  for (int r=0;r<16;r++) out[(row0+r)*D_ + tid] = acc[r];
}

// one block per node: gather in-edges, add self loop + bias; block-level sum/sumsq partials
__global__ __launch_bounds__(256) void k_agg(const float* __restrict__ A,
    const int* __restrict__ rowptr, const int* __restrict__ col,
    const float* __restrict__ dinv, const float* __restrict__ bvec,
    float* __restrict__ out, float* __restrict__ partS, float* __restrict__ partQ){
  int v = blockIdx.x; int t = threadIdx.x;
  float dv  = dinv[v];
  float acc = dv * A[v*D_ + t];
  int j0 = rowptr[v], j1 = rowptr[v+1];
  for (int j=j0;j<j1;j++){
    int s = col[j];
    acc += dinv[s] * A[s*D_ + t];
  }
  float val = dv*acc + bvec[t];
  out[v*D_ + t] = val;

  __shared__ float s1[256], s2[256];
  s1[t] = val; s2[t] = val*val; __syncthreads();
  #pragma unroll
  for (int off=128; off>0; off>>=1){
    if (t < off){ s1[t]+=s1[t+off]; s2[t]+=s2[t+off]; }
    __syncthreads();
  }
  if (t==0){ partS[v]=s1[0]; partQ[v]=s2[0]; }
}

// deterministic final reduction of 32768 partials -> mean, 1/(std+eps)
__global__ void k_stats(const float* __restrict__ partS, const float* __restrict__ partQ,
                        float* __restrict__ stats){
  __shared__ float s1[1024], s2[1024];
  int t = threadIdx.x;
  float a=0.f, b=0.f;
  for (int i=t; i<NT_; i+=1024){ a += partS[i]; b += partQ[i]; }
  s1[t]=a; s2[t]=b; __syncthreads();
  for (int off=512; off>0; off>>=1){
    if (t<off){ s1[t]+=s1[t+off]; s2[t]+=s2[t+off]; }
    __syncthreads();
  }
  if (t==0){
    float mean = s1[0] / (float)NP_;
    float var  = s2[0] / (float)NP_ - mean*mean;
    var = var > 0.f ? var : 0.f;
    stats[0] = mean;
    stats[1] = 1.0f / (sqrtf(var) + EPS_);
  }
}

// y = prelu(g*( (x-mean)*inv ) + be), vectorized float4
__global__ void k_norm(const float* __restrict__ in, const float* __restrict__ g,
                       const float* __restrict__ be, const float* __restrict__ aP,
                       const float* __restrict__ stats, float* __restrict__ out){
  float mean = stats[0], inv = stats[1], a = aP[0];
  int gid  = blockIdx.x*blockDim.x + threadIdx.x;
  int base = gid*4;
  int c    = base & (D_-1);
  float4 v  = *(const float4*)&in[base];
  float4 gg = *(const float4*)&g[c];
  float4 bb = *(const float4*)&be[c];
  float4 o;
  o.x = gg.x*((v.x-mean)*inv)+bb.x; o.x = o.x>=0.f ? o.x : a*o.x;
  o.y = gg.y*((v.y-mean)*inv)+bb.y; o.y = o.y>=0.f ? o.y : a*o.y;
  o.z = gg.z*((v.z-mean)*inv)+bb.z; o.z = o.z>=0.f ? o.z : a*o.z;
  o.w = gg.w*((v.w-mean)*inv)+bb.w; o.w = o.w>=0.f ? o.w : a*o.w;
  *(float4*)&out[base] = o;
}

// ---------------- launch ----------------

extern "C" void kernel_launch(void* const* d_in, const int* in_sizes, int n_in,
                              void* d_out, int out_size, void* d_ws, size_t ws_size,
                              hipStream_t stream){
  const float* x    = (const float*)d_in[0];
  const int*   knn  = (const int*)  d_in[1];
  const void*  mask =               d_in[2];
  const float* W0   = (const float*)d_in[3];
  const float* b0   = (const float*)d_in[4];
  const float* g0   = (const float*)d_in[5];
  const float* be0  = (const float*)d_in[6];
  const float* a0   = (const float*)d_in[7];
  const float* W1   = (const float*)d_in[8];
  const float* b1   = (const float*)d_in[9];
  const float* g1   = (const float*)d_in[10];
  const float* be1  = (const float*)d_in[11];
  const float* a1   = (const float*)d_in[12];
  float* out = (float*)d_out;

  char* w = (char*)d_ws;
  size_t off = 0;
  auto alloc = [&](size_t bytes)->void*{
    void* p = w + off; off = (off + bytes + 255) & ~(size_t)255; return p;
  };
  int*   degcnt  = (int*)  alloc(NT_*4);
  int*   rowptr  = (int*)  alloc((NT_+1)*4);
  int*   fillptr = (int*)  alloc(NT_*4);
  int*   col     = (int*)  alloc(E16_*4);
  float* dinv    = (float*)alloc(NT_*4);
  float* partS   = (float*)alloc(NT_*4);
  float* partQ   = (float*)alloc(NT_*4);
  float* stats   = (float*)alloc(4*4);
  int*   flag    = (int*)  alloc(4);
  float* A       = (float*)alloc((size_t)NP_*4);
  float* Bagg    = (float*)alloc((size_t)NP_*4);

  // edge structure (shared by both layers)
  hipLaunchKernelGGL(k_zero,   dim3(NT_/256),  dim3(256), 0, stream, degcnt);
  hipLaunchKernelGGL(k_detect, dim3(1),        dim3(64),  0, stream, (const unsigned int*)mask, flag);
  hipLaunchKernelGGL(k_deg,    dim3(E16_/256), dim3(256), 0, stream, knn, mask, flag, degcnt);
  hipLaunchKernelGGL(k_scan,   dim3(1),        dim3(1024),0, stream, degcnt, rowptr, fillptr, dinv);
  hipLaunchKernelGGL(k_fill,   dim3(E16_/256), dim3(256), 0, stream, knn, mask, flag, fillptr, col);

  // layer 0 (input: x[:,0,:], row stride 512)
  hipLaunchKernelGGL(k_gemm,  dim3(NT_/16),  dim3(256), 0, stream, x, 512, W0, A);
  hipLaunchKernelGGL(k_agg,   dim3(NT_),     dim3(256), 0, stream, A, rowptr, col, dinv, b0, Bagg, partS, partQ);
  hipLaunchKernelGGL(k_stats, dim3(1),       dim3(1024),0, stream, partS, partQ, stats);
  hipLaunchKernelGGL(k_norm,  dim3(NP_/1024),dim3(256), 0, stream, Bagg, g0, be0, a0, stats, Bagg);

  // layer 1
  hipLaunchKernelGGL(k_gemm,  dim3(NT_/16),  dim3(256), 0, stream, Bagg, 256, W1, A);
  hipLaunchKernelGGL(k_agg,   dim3(NT_),     dim3(256), 0, stream, A, rowptr, col, dinv, b1, Bagg, partS, partQ);
  hipLaunchKernelGGL(k_stats, dim3(1),       dim3(1024),0, stream, partS, partQ, stats);
  hipLaunchKernelGGL(k_norm,  dim3(NP_/1024),dim3(256), 0, stream, Bagg, g1, be1, a1, stats, out);
}

// Round 2
// 309.816 us; speedup vs baseline: 2.7673x; 2.7673x over previous
//
#include <hip/hip_runtime.h>
#include <hip/hip_bf16.h>
#include <stdint.h>

#define B_   8
#define N_   4096
#define K1_  17
#define D_   256
#define NT_  (B_*N_)          // 32768
#define E16_ (NT_*16)         // 524288
#define NP_  (NT_*D_)         // 8388608
#define EPS_ 1e-5f

typedef __attribute__((ext_vector_type(8))) short short8v;  // 8 bf16 (4 VGPR)
typedef __attribute__((ext_vector_type(4))) short short4v;
typedef __attribute__((ext_vector_type(4))) float f32x4;

__device__ __forceinline__ short f2bf(float f){
  unsigned u = __float_as_uint(f);
  unsigned r = (u + 0x7FFFu + ((u>>16)&1u)) >> 16;   // RNE
  return (short)r;
}
__device__ __forceinline__ float bf2f(short s){
  return __uint_as_float(((unsigned)(unsigned short)s) << 16);
}

// ---------------- edge-structure kernels ----------------

__global__ void k_zero(int* __restrict__ degcnt){
  int i = blockIdx.x*blockDim.x + threadIdx.x;
  if (i < NT_) degcnt[i] = 0;
}

// Detect edge_mask storage: 0 = int32 {0,1}, 1 = float32 {0.f,1.f}, 2 = uint8/bool
__global__ void k_detect(const unsigned int* __restrict__ mw, int* __restrict__ flag){
  if (threadIdx.x==0 && blockIdx.x==0){
    int isInt=1, isF32=1;
    for (int i=0;i<1024;i++){
      unsigned w = mw[i];
      if (!(w==0u || w==1u)) isInt=0;
      if (!(w==0u || w==0x3F800000u)) isF32=0;
    }
    *flag = isInt ? 0 : (isF32 ? 1 : 2);
  }
}

__device__ __forceinline__ bool mask_at(const void* maskp, int f, int idx){
  if (f==0) return ((const int*)maskp)[idx] != 0;
  if (f==1) return ((const float*)maskp)[idx] != 0.0f;
  return ((const unsigned char*)maskp)[idx] != 0;
}

__global__ void k_deg(const int* __restrict__ knn, const void* __restrict__ maskp,
                      const int* __restrict__ flag, int* __restrict__ degcnt){
  int f = *flag;
  int e = blockIdx.x*blockDim.x + threadIdx.x;
  if (e >= E16_) return;
  int node = e >> 4;            // b*N + n
  int k    = (e & 15) + 1;      // skip k=0
  int idx  = node*K1_ + k;
  if (mask_at(maskp, f, idx)){
    int b   = node >> 12;
    int dst = knn[idx] + (b<<12);
    atomicAdd(&degcnt[dst], 1);
  }
}

__global__ void k_scan(const int* __restrict__ degcnt, int* __restrict__ rowptr,
                       int* __restrict__ fillptr, float* __restrict__ dinv){
  __shared__ int sm[1024];
  int t = threadIdx.x;
  int base = t*32;
  int loc[32]; int tot = 0;
  #pragma unroll
  for (int i=0;i<32;i++){ loc[i] = degcnt[base+i]; tot += loc[i]; }
  sm[t] = tot; __syncthreads();
  for (int off=1; off<1024; off<<=1){
    int v = (t>=off) ? sm[t-off] : 0;
    __syncthreads();
    sm[t] += v;
    __syncthreads();
  }
  int run = sm[t] - tot;
  #pragma unroll
  for (int i=0;i<32;i++){
    int v = base+i;
    rowptr[v]  = run;
    fillptr[v] = run;
    dinv[v]    = rsqrtf((float)loc[i] + 1.0f);
    run += loc[i];
  }
  if (t==1023) rowptr[NT_] = run;
}

__global__ void k_fill(const int* __restrict__ knn, const void* __restrict__ maskp,
                       const int* __restrict__ flag, int* __restrict__ fillptr,
                       int* __restrict__ col){
  int f = *flag;
  int e = blockIdx.x*blockDim.x + threadIdx.x;
  if (e >= E16_) return;
  int node = e >> 4;
  int k    = (e & 15) + 1;
  int idx  = node*K1_ + k;
  if (mask_at(maskp, f, idx)){
    int b   = node >> 12;
    int dst = knn[idx] + (b<<12);
    int pos = atomicAdd(&fillptr[dst], 1);
    col[pos] = node;
  }
}

// ---------------- conversion kernels ----------------

// x[:,0,:] (row stride 512 f32) -> Hb bf16 [NT][256]
__global__ __launch_bounds__(256) void k_cvt_x(const float* __restrict__ x,
                                               short* __restrict__ Hb){
  int gid = blockIdx.x*256 + threadIdx.x;
  int row = gid >> 6;           // 64 threads per row
  int col = (gid & 63) * 4;
  float4 v = *(const float4*)&x[(size_t)row*512 + col];
  short4v o = { f2bf(v.x), f2bf(v.y), f2bf(v.z), f2bf(v.w) };
  *(short4v*)&Hb[(size_t)row*256 + col] = o;
}

// Wt[n][k] = bf16(W[k][n])
__global__ __launch_bounds__(256) void k_cvt_w(const float* __restrict__ W,
                                               short* __restrict__ Wt){
  int n = blockIdx.x, k = threadIdx.x;
  Wt[n*256 + k] = f2bf(W[k*256 + n]);
}

// ---------------- MFMA GEMM: Ab[r][c] = bf16( sum_k Hb[r][k]*W[k][c] ) ----------------
// block = 256 thr = 4 waves; wave w does rows [blk*64 + w*16, +16) x all 256 cols.
// A frag: lane l holds Hb[row0 + (l&15)][ks*32 + 8*(l>>4) + j], j=0..7 (contiguous b128)
// B frag: lane l holds W[ks*32 + 8*(l>>4)+j][nt*16 + (l&15)] = Wt[nt*16+(l&15)][...]
// D frag: lane l reg r -> D[4*(l>>4)+r][nt*16 + (l&15)]
__global__ __launch_bounds__(256) void k_gemm_mfma(const short* __restrict__ Hb,
                                                   const short* __restrict__ Wt,
                                                   short* __restrict__ Ab){
  int wave = threadIdx.x >> 6;
  int lane = threadIdx.x & 63;
  int lr   = lane & 15;
  int lk   = (lane >> 4) * 8;
  int row0 = blockIdx.x*64 + wave*16;

  f32x4 acc[16];
  #pragma unroll
  for (int i=0;i<16;i++) acc[i] = (f32x4){0.f,0.f,0.f,0.f};

  const short* aRow = Hb + (size_t)(row0 + lr)*256 + lk;
  #pragma unroll
  for (int ks=0; ks<8; ks++){
    short8v a = *(const short8v*)(aRow + ks*32);
    #pragma unroll
    for (int nt=0; nt<16; nt++){
      short8v b = *(const short8v*)(Wt + (size_t)(nt*16 + lr)*256 + ks*32 + lk);
      acc[nt] = __builtin_amdgcn_mfma_f32_16x16x32_bf16(a, b, acc[nt], 0, 0, 0);
    }
  }

  int mbase = (lane >> 4) * 4;
  #pragma unroll
  for (int nt=0; nt<16; nt++){
    #pragma unroll
    for (int r=0;r<4;r++){
      Ab[(size_t)(row0 + mbase + r)*256 + nt*16 + lr] = f2bf(acc[nt][r]);
    }
  }
}

// ---------------- aggregation: 32 lanes per node, 8 cols/lane ----------------
__global__ __launch_bounds__(256) void k_agg(const short* __restrict__ Ab,
    const int* __restrict__ rowptr, const int* __restrict__ col,
    const float* __restrict__ dinv, const float* __restrict__ bvec,
    float* __restrict__ out, float* __restrict__ partS, float* __restrict__ partQ){
  int node = blockIdx.x*8 + (threadIdx.x >> 5);
  int sub  = threadIdx.x & 31;          // handles cols sub*8 .. sub*8+7
  int c0   = sub*8;
  float dv = dinv[node];

  float acc[8];
  {
    short8v s = *(const short8v*)&Ab[(size_t)node*256 + c0];
    #pragma unroll
    for (int i=0;i<8;i++) acc[i] = dv * bf2f(s[i]);
  }
  int j0 = rowptr[node], j1 = rowptr[node+1];
  for (int j=j0;j<j1;j++){
    int s = col[j];
    float ds = dinv[s];
    short8v nb = *(const short8v*)&Ab[(size_t)s*256 + c0];
    #pragma unroll
    for (int i=0;i<8;i++) acc[i] += ds * bf2f(nb[i]);
  }
  float sum=0.f, sq=0.f;
  float4 o0, o1;
  float* op[2] = {&o0.x, &o1.x};
  #pragma unroll
  for (int i=0;i<8;i++){
    float v = dv*acc[i] + bvec[c0+i];
    op[i>>2][i&3] = v;
    sum += v; sq += v*v;
  }
  *(float4*)&out[(size_t)node*256 + c0]     = o0;
  *(float4*)&out[(size_t)node*256 + c0 + 4] = o1;

  #pragma unroll
  for (int off=16; off>0; off>>=1){
    sum += __shfl_down(sum, off, 32);
    sq  += __shfl_down(sq,  off, 32);
  }
  if (sub==0){ partS[node]=sum; partQ[node]=sq; }
}

// ---------------- stats (double accumulation) ----------------
__global__ void k_stats(const float* __restrict__ partS, const float* __restrict__ partQ,
                        float* __restrict__ stats){
  __shared__ double s1[1024], s2[1024];
  int t = threadIdx.x;
  double a=0.0, b=0.0;
  for (int i=t; i<NT_; i+=1024){ a += (double)partS[i]; b += (double)partQ[i]; }
  s1[t]=a; s2[t]=b; __syncthreads();
  for (int off=512; off>0; off>>=1){
    if (t<off){ s1[t]+=s1[t+off]; s2[t]+=s2[t+off]; }
    __syncthreads();
  }
  if (t==0){
    double mean = s1[0] / (double)NP_;
    double var  = s2[0] / (double)NP_ - mean*mean;
    var = var > 0.0 ? var : 0.0;
    stats[0] = (float)mean;
    stats[1] = (float)(1.0 / (sqrt(var) + (double)EPS_));
  }
}

// ---------------- norm + prelu ----------------
__global__ void k_norm_f32(const float* __restrict__ in, const float* __restrict__ g,
                           const float* __restrict__ be, const float* __restrict__ aP,
                           const float* __restrict__ stats, float* __restrict__ out){
  float mean = stats[0], inv = stats[1], a = aP[0];
  int gid  = blockIdx.x*blockDim.x + threadIdx.x;
  int base = gid*4;
  int c    = base & (D_-1);
  float4 v  = *(const float4*)&in[base];
  float4 gg = *(const float4*)&g[c];
  float4 bb = *(const float4*)&be[c];
  float4 o;
  o.x = gg.x*((v.x-mean)*inv)+bb.x; o.x = o.x>=0.f ? o.x : a*o.x;
  o.y = gg.y*((v.y-mean)*inv)+bb.y; o.y = o.y>=0.f ? o.y : a*o.y;
  o.z = gg.z*((v.z-mean)*inv)+bb.z; o.z = o.z>=0.f ? o.z : a*o.z;
  o.w = gg.w*((v.w-mean)*inv)+bb.w; o.w = o.w>=0.f ? o.w : a*o.w;
  *(float4*)&out[base] = o;
}

__global__ void k_norm_bf16(const float* __restrict__ in, const float* __restrict__ g,
                            const float* __restrict__ be, const float* __restrict__ aP,
                            const float* __restrict__ stats, short* __restrict__ out){
  float mean = stats[0], inv = stats[1], a = aP[0];
  int gid  = blockIdx.x*blockDim.x + threadIdx.x;
  int base = gid*4;
  int c    = base & (D_-1);
  float4 v  = *(const float4*)&in[base];
  float4 gg = *(const float4*)&g[c];
  float4 bb = *(const float4*)&be[c];
  float ox = gg.x*((v.x-mean)*inv)+bb.x; ox = ox>=0.f ? ox : a*ox;
  float oy = gg.y*((v.y-mean)*inv)+bb.y; oy = oy>=0.f ? oy : a*oy;
  float oz = gg.z*((v.z-mean)*inv)+bb.z; oz = oz>=0.f ? oz : a*oz;
  float ow = gg.w*((v.w-mean)*inv)+bb.w; ow = ow>=0.f ? ow : a*ow;
  short4v o = { f2bf(ox), f2bf(oy), f2bf(oz), f2bf(ow) };
  *(short4v*)&out[base] = o;
}

// ---------------- launch ----------------

extern "C" void kernel_launch(void* const* d_in, const int* in_sizes, int n_in,
                              void* d_out, int out_size, void* d_ws, size_t ws_size,
                              hipStream_t stream){
  const float* x    = (const float*)d_in[0];
  const int*   knn  = (const int*)  d_in[1];
  const void*  mask =               d_in[2];
  const float* W0   = (const float*)d_in[3];
  const float* b0   = (const float*)d_in[4];
  const float* g0   = (const float*)d_in[5];
  const float* be0  = (const float*)d_in[6];
  const float* a0   = (const float*)d_in[7];
  const float* W1   = (const float*)d_in[8];
  const float* b1   = (const float*)d_in[9];
  const float* g1   = (const float*)d_in[10];
  const float* be1  = (const float*)d_in[11];
  const float* a1   = (const float*)d_in[12];
  float* out = (float*)d_out;

  char* w = (char*)d_ws;
  size_t off = 0;
  auto alloc = [&](size_t bytes)->void*{
    void* p = w + off; off = (off + bytes + 255) & ~(size_t)255; return p;
  };
  int*   degcnt  = (int*)  alloc(NT_*4);
  int*   rowptr  = (int*)  alloc((NT_+1)*4);
  int*   fillptr = (int*)  alloc(NT_*4);
  int*   col     = (int*)  alloc(E16_*4);
  float* dinv    = (float*)alloc(NT_*4);
  float* partS   = (float*)alloc(NT_*4);
  float* partQ   = (float*)alloc(NT_*4);
  float* stats   = (float*)alloc(4*4);
  int*   flag    = (int*)  alloc(4);
  short* Hb      = (short*)alloc((size_t)NP_*2);   // bf16 layer input
  short* Ab      = (short*)alloc((size_t)NP_*2);   // bf16 gemm output
  short* Wt      = (short*)alloc(256*256*2);       // bf16 W^T
  float* Bagg    = (float*)alloc((size_t)NP_*4);   // f32 aggregated

  // edge structure
  hipLaunchKernelGGL(k_zero,   dim3(NT_/256),  dim3(256), 0, stream, degcnt);
  hipLaunchKernelGGL(k_detect, dim3(1),        dim3(64),  0, stream, (const unsigned int*)mask, flag);
  hipLaunchKernelGGL(k_deg,    dim3(E16_/256), dim3(256), 0, stream, knn, mask, flag, degcnt);
  hipLaunchKernelGGL(k_scan,   dim3(1),        dim3(1024),0, stream, degcnt, rowptr, fillptr, dinv);
  hipLaunchKernelGGL(k_fill,   dim3(E16_/256), dim3(256), 0, stream, knn, mask, flag, fillptr, col);

  // layer 0
  hipLaunchKernelGGL(k_cvt_x,  dim3(NT_/4),    dim3(256), 0, stream, x, Hb);
  hipLaunchKernelGGL(k_cvt_w,  dim3(256),      dim3(256), 0, stream, W0, Wt);
  hipLaunchKernelGGL(k_gemm_mfma, dim3(NT_/64),dim3(256), 0, stream, Hb, Wt, Ab);
  hipLaunchKernelGGL(k_agg,    dim3(NT_/8),    dim3(256), 0, stream, Ab, rowptr, col, dinv, b0, Bagg, partS, partQ);
  hipLaunchKernelGGL(k_stats,  dim3(1),        dim3(1024),0, stream, partS, partQ, stats);
  hipLaunchKernelGGL(k_norm_bf16, dim3(NP_/1024), dim3(256), 0, stream, Bagg, g0, be0, a0, stats, Hb);

  // layer 1
  hipLaunchKernelGGL(k_cvt_w,  dim3(256),      dim3(256), 0, stream, W1, Wt);
  hipLaunchKernelGGL(k_gemm_mfma, dim3(NT_/64),dim3(256), 0, stream, Hb, Wt, Ab);
  hipLaunchKernelGGL(k_agg,    dim3(NT_/8),    dim3(256), 0, stream, Ab, rowptr, col, dinv, b1, Bagg, partS, partQ);
  hipLaunchKernelGGL(k_stats,  dim3(1),        dim3(1024),0, stream, partS, partQ, stats);
  hipLaunchKernelGGL(k_norm_f32,  dim3(NP_/1024), dim3(256), 0, stream, Bagg, g1, be1, a1, stats, out);
}

// Round 3
// 234.699 us; speedup vs baseline: 3.6530x; 1.3201x over previous
//
#include <hip/hip_runtime.h>
#include <hip/hip_bf16.h>
#include <stdint.h>

#define B_   8
#define N_   4096
#define K1_  17
#define D_   256
#define NT_  (B_*N_)          // 32768
#define E16_ (NT_*16)         // 524288
#define NP_  (NT_*D_)         // 8388608
#define EPS_ 1e-5f

typedef __attribute__((ext_vector_type(8))) short short8v;  // 8 bf16 (4 VGPR)
typedef __attribute__((ext_vector_type(4))) short short4v;
typedef __attribute__((ext_vector_type(4))) float f32x4;

__device__ __forceinline__ short f2bf(float f){
  unsigned u = __float_as_uint(f);
  unsigned r = (u + 0x7FFFu + ((u>>16)&1u)) >> 16;   // RNE
  return (short)r;
}
__device__ __forceinline__ float bf2f(short s){
  return __uint_as_float(((unsigned)(unsigned short)s) << 16);
}

// ---------------- edge-structure kernels ----------------

__global__ void k_zero(int* __restrict__ degcnt){
  int i = blockIdx.x*blockDim.x + threadIdx.x;
  if (i < NT_) degcnt[i] = 0;
}

// Detect edge_mask storage: 0 = int32 {0,1}, 1 = float32 {0.f,1.f}, 2 = uint8/bool
// parallel: 1024 threads each check one word, LDS atomicAnd
__global__ __launch_bounds__(1024) void k_detect(const unsigned int* __restrict__ mw,
                                                 int* __restrict__ flag){
  __shared__ int s_int, s_f32;
  int t = threadIdx.x;
  if (t==0){ s_int=1; s_f32=1; }
  __syncthreads();
  unsigned w = mw[t];
  if (!(w==0u || w==1u))          atomicAnd(&s_int, 0);
  if (!(w==0u || w==0x3F800000u)) atomicAnd(&s_f32, 0);
  __syncthreads();
  if (t==0) *flag = s_int ? 0 : (s_f32 ? 1 : 2);
}

__device__ __forceinline__ bool mask_at(const void* maskp, int f, int idx){
  if (f==0) return ((const int*)maskp)[idx] != 0;
  if (f==1) return ((const float*)maskp)[idx] != 0.0f;
  return ((const unsigned char*)maskp)[idx] != 0;
}

__global__ void k_deg(const int* __restrict__ knn, const void* __restrict__ maskp,
                      const int* __restrict__ flag, int* __restrict__ degcnt){
  int f = *flag;
  int e = blockIdx.x*blockDim.x + threadIdx.x;
  if (e >= E16_) return;
  int node = e >> 4;            // b*N + n
  int k    = (e & 15) + 1;      // skip k=0
  int idx  = node*K1_ + k;
  if (mask_at(maskp, f, idx)){
    int b   = node >> 12;
    int dst = knn[idx] + (b<<12);
    atomicAdd(&degcnt[dst], 1);
  }
}

__global__ void k_scan(const int* __restrict__ degcnt, int* __restrict__ rowptr,
                       int* __restrict__ fillptr, float* __restrict__ dinv){
  __shared__ int sm[1024];
  int t = threadIdx.x;
  int base = t*32;
  int loc[32]; int tot = 0;
  #pragma unroll
  for (int i=0;i<32;i++){ loc[i] = degcnt[base+i]; tot += loc[i]; }
  sm[t] = tot; __syncthreads();
  for (int off=1; off<1024; off<<=1){
    int v = (t>=off) ? sm[t-off] : 0;
    __syncthreads();
    sm[t] += v;
    __syncthreads();
  }
  int run = sm[t] - tot;
  #pragma unroll
  for (int i=0;i<32;i++){
    int v = base+i;
    rowptr[v]  = run;
    fillptr[v] = run;
    dinv[v]    = rsqrtf((float)loc[i] + 1.0f);
    run += loc[i];
  }
  if (t==1023) rowptr[NT_] = run;
}

__global__ void k_fill(const int* __restrict__ knn, const void* __restrict__ maskp,
                       const int* __restrict__ flag, int* __restrict__ fillptr,
                       int* __restrict__ col){
  int f = *flag;
  int e = blockIdx.x*blockDim.x + threadIdx.x;
  if (e >= E16_) return;
  int node = e >> 4;
  int k    = (e & 15) + 1;
  int idx  = node*K1_ + k;
  if (mask_at(maskp, f, idx)){
    int b   = node >> 12;
    int dst = knn[idx] + (b<<12);
    int pos = atomicAdd(&fillptr[dst], 1);
    col[pos] = node;
  }
}

// ---------------- conversion kernels ----------------

__global__ __launch_bounds__(256) void k_cvt_x(const float* __restrict__ x,
                                               short* __restrict__ Hb){
  int gid = blockIdx.x*256 + threadIdx.x;
  int row = gid >> 6;
  int col = (gid & 63) * 4;
  float4 v = *(const float4*)&x[(size_t)row*512 + col];
  short4v o = { f2bf(v.x), f2bf(v.y), f2bf(v.z), f2bf(v.w) };
  *(short4v*)&Hb[(size_t)row*256 + col] = o;
}

__global__ __launch_bounds__(256) void k_cvt_w(const float* __restrict__ W,
                                               short* __restrict__ Wt){
  int n = blockIdx.x, k = threadIdx.x;
  Wt[n*256 + k] = f2bf(W[k*256 + n]);
}

// ---------------- MFMA GEMM, B-resident-in-registers ----------------
// 512 threads = 8 waves. Wave w owns col strips {2w, 2w+1} (32 cols).
// Prologue: load 16 B-frags (8 ks x 2 strips) into VGPRs, reused for all rows.
// Loop: 4 row-tiles of 16 rows; per tile 8 A-loads (shared by both strips), 16 MFMA.
// A frag: lane l holds Hb[row0+(l&15)][ks*32 + 8*(l>>4) + j]
// B frag: lane l holds Wt[strip*16+(l&15)][ks*32 + 8*(l>>4) + j]
// D frag: lane l reg r -> D[row0 + 4*(l>>4)+r][strip*16 + (l&15)]
__global__ __launch_bounds__(512) void k_gemm_mfma(const short* __restrict__ Hb,
                                                   const short* __restrict__ Wt,
                                                   short* __restrict__ Ab){
  int wave = threadIdx.x >> 6;
  int lane = threadIdx.x & 63;
  int lr   = lane & 15;
  int lk   = (lane >> 4) * 8;
  int s0   = wave*2, s1 = wave*2 + 1;

  short8v b0[8], b1[8];
  const short* w0p = Wt + (size_t)(s0*16 + lr)*256 + lk;
  const short* w1p = Wt + (size_t)(s1*16 + lr)*256 + lk;
  #pragma unroll
  for (int ks=0; ks<8; ks++){
    b0[ks] = *(const short8v*)(w0p + ks*32);
    b1[ks] = *(const short8v*)(w1p + ks*32);
  }

  int rowB = blockIdx.x*64;
  #pragma unroll
  for (int rt=0; rt<4; rt++){
    int row0 = rowB + rt*16;
    const short* aRow = Hb + (size_t)(row0 + lr)*256 + lk;
    f32x4 acc0 = (f32x4){0.f,0.f,0.f,0.f};
    f32x4 acc1 = (f32x4){0.f,0.f,0.f,0.f};
    #pragma unroll
    for (int ks=0; ks<8; ks++){
      short8v a = *(const short8v*)(aRow + ks*32);
      acc0 = __builtin_amdgcn_mfma_f32_16x16x32_bf16(a, b0[ks], acc0, 0, 0, 0);
      acc1 = __builtin_amdgcn_mfma_f32_16x16x32_bf16(a, b1[ks], acc1, 0, 0, 0);
    }
    int mrow = row0 + (lane>>4)*4;
    #pragma unroll
    for (int r=0;r<4;r++){
      Ab[(size_t)(mrow + r)*256 + s0*16 + lr] = f2bf(acc0[r]);
      Ab[(size_t)(mrow + r)*256 + s1*16 + lr] = f2bf(acc1[r]);
    }
  }
}

// ---------------- aggregation: 32 lanes per node, XCD-swizzled blocks ----------------
// 4096 blocks; swizzle so XCD x gets blocks [x*512, (x+1)*512) = batch x (2MB, L2-fit)
__global__ __launch_bounds__(256) void k_agg(const short* __restrict__ Ab,
    const int* __restrict__ rowptr, const int* __restrict__ col,
    const float* __restrict__ dinv, const float* __restrict__ bvec,
    float* __restrict__ out, float* __restrict__ partS, float* __restrict__ partQ){
  int bid  = (int)(blockIdx.x & 7) * 512 + (int)(blockIdx.x >> 3);  // XCD swizzle
  int node = bid*8 + (threadIdx.x >> 5);
  int sub  = threadIdx.x & 31;
  int c0   = sub*8;
  float dv = dinv[node];

  float acc[8];
  {
    short8v s = *(const short8v*)&Ab[(size_t)node*256 + c0];
    #pragma unroll
    for (int i=0;i<8;i++) acc[i] = dv * bf2f(s[i]);
  }
  int j0 = rowptr[node], j1 = rowptr[node+1];
  for (int j=j0;j<j1;j++){
    int s = col[j];
    float ds = dinv[s];
    short8v nb = *(const short8v*)&Ab[(size_t)s*256 + c0];
    #pragma unroll
    for (int i=0;i<8;i++) acc[i] += ds * bf2f(nb[i]);
  }
  float sum=0.f, sq=0.f;
  float4 o0, o1;
  float* op[2] = {&o0.x, &o1.x};
  #pragma unroll
  for (int i=0;i<8;i++){
    float v = dv*acc[i] + bvec[c0+i];
    op[i>>2][i&3] = v;
    sum += v; sq += v*v;
  }
  *(float4*)&out[(size_t)node*256 + c0]     = o0;
  *(float4*)&out[(size_t)node*256 + c0 + 4] = o1;

  #pragma unroll
  for (int off=16; off>0; off>>=1){
    sum += __shfl_down(sum, off, 32);
    sq  += __shfl_down(sq,  off, 32);
  }
  if (sub==0){ partS[node]=sum; partQ[node]=sq; }
}

// ---------------- stats (double accumulation) ----------------
__global__ void k_stats(const float* __restrict__ partS, const float* __restrict__ partQ,
                        float* __restrict__ stats){
  __shared__ double s1[1024], s2[1024];
  int t = threadIdx.x;
  double a=0.0, b=0.0;
  for (int i=t; i<NT_; i+=1024){ a += (double)partS[i]; b += (double)partQ[i]; }
  s1[t]=a; s2[t]=b; __syncthreads();
  for (int off=512; off>0; off>>=1){
    if (t<off){ s1[t]+=s1[t+off]; s2[t]+=s2[t+off]; }
    __syncthreads();
  }
  if (t==0){
    double mean = s1[0] / (double)NP_;
    double var  = s2[0] / (double)NP_ - mean*mean;
    var = var > 0.0 ? var : 0.0;
    stats[0] = (float)mean;
    stats[1] = (float)(1.0 / (sqrt(var) + (double)EPS_));
  }
}

// ---------------- norm + prelu ----------------
__global__ void k_norm_f32(const float* __restrict__ in, const float* __restrict__ g,
                           const float* __restrict__ be, const float* __restrict__ aP,
                           const float* __restrict__ stats, float* __restrict__ out){
  float mean = stats[0], inv = stats[1], a = aP[0];
  int gid  = blockIdx.x*blockDim.x + threadIdx.x;
  int base = gid*4;
  int c    = base & (D_-1);
  float4 v  = *(const float4*)&in[base];
  float4 gg = *(const float4*)&g[c];
  float4 bb = *(const float4*)&be[c];
  float4 o;
  o.x = gg.x*((v.x-mean)*inv)+bb.x; o.x = o.x>=0.f ? o.x : a*o.x;
  o.y = gg.y*((v.y-mean)*inv)+bb.y; o.y = o.y>=0.f ? o.y : a*o.y;
  o.z = gg.z*((v.z-mean)*inv)+bb.z; o.z = o.z>=0.f ? o.z : a*o.z;
  o.w = gg.w*((v.w-mean)*inv)+bb.w; o.w = o.w>=0.f ? o.w : a*o.w;
  *(float4*)&out[base] = o;
}

__global__ void k_norm_bf16(const float* __restrict__ in, const float* __restrict__ g,
                            const float* __restrict__ be, const float* __restrict__ aP,
                            const float* __restrict__ stats, short* __restrict__ out){
  float mean = stats[0], inv = stats[1], a = aP[0];
  int gid  = blockIdx.x*blockDim.x + threadIdx.x;
  int base = gid*4;
  int c    = base & (D_-1);
  float4 v  = *(const float4*)&in[base];
  float4 gg = *(const float4*)&g[c];
  float4 bb = *(const float4*)&be[c];
  float ox = gg.x*((v.x-mean)*inv)+bb.x; ox = ox>=0.f ? ox : a*ox;
  float oy = gg.y*((v.y-mean)*inv)+bb.y; oy = oy>=0.f ? oy : a*oy;
  float oz = gg.z*((v.z-mean)*inv)+bb.z; oz = oz>=0.f ? oz : a*oz;
  float ow = gg.w*((v.w-mean)*inv)+bb.w; ow = ow>=0.f ? ow : a*ow;
  short4v o = { f2bf(ox), f2bf(oy), f2bf(oz), f2bf(ow) };
  *(short4v*)&out[base] = o;
}

// ---------------- launch ----------------

extern "C" void kernel_launch(void* const* d_in, const int* in_sizes, int n_in,
                              void* d_out, int out_size, void* d_ws, size_t ws_size,
                              hipStream_t stream){
  const float* x    = (const float*)d_in[0];
  const int*   knn  = (const int*)  d_in[1];
  const void*  mask =               d_in[2];
  const float* W0   = (const float*)d_in[3];
  const float* b0   = (const float*)d_in[4];
  const float* g0   = (const float*)d_in[5];
  const float* be0  = (const float*)d_in[6];
  const float* a0   = (const float*)d_in[7];
  const float* W1   = (const float*)d_in[8];
  const float* b1   = (const float*)d_in[9];
  const float* g1   = (const float*)d_in[10];
  const float* be1  = (const float*)d_in[11];
  const float* a1   = (const float*)d_in[12];
  float* out = (float*)d_out;

  char* w = (char*)d_ws;
  size_t off = 0;
  auto alloc = [&](size_t bytes)->void*{
    void* p = w + off; off = (off + bytes + 255) & ~(size_t)255; return p;
  };
  int*   degcnt  = (int*)  alloc(NT_*4);
  int*   rowptr  = (int*)  alloc((NT_+1)*4);
  int*   fillptr = (int*)  alloc(NT_*4);
  int*   col     = (int*)  alloc(E16_*4);
  float* dinv    = (float*)alloc(NT_*4);
  float* partS   = (float*)alloc(NT_*4);
  float* partQ   = (float*)alloc(NT_*4);
  float* stats   = (float*)alloc(4*4);
  int*   flag    = (int*)  alloc(4);
  short* Hb      = (short*)alloc((size_t)NP_*2);
  short* Ab      = (short*)alloc((size_t)NP_*2);
  short* Wt      = (short*)alloc(256*256*2);
  float* Bagg    = (float*)alloc((size_t)NP_*4);

  // edge structure
  hipLaunchKernelGGL(k_zero,   dim3(NT_/256),  dim3(256), 0, stream, degcnt);
  hipLaunchKernelGGL(k_detect, dim3(1),        dim3(1024),0, stream, (const unsigned int*)mask, flag);
  hipLaunchKernelGGL(k_deg,    dim3(E16_/256), dim3(256), 0, stream, knn, mask, flag, degcnt);
  hipLaunchKernelGGL(k_scan,   dim3(1),        dim3(1024),0, stream, degcnt, rowptr, fillptr, dinv);
  hipLaunchKernelGGL(k_fill,   dim3(E16_/256), dim3(256), 0, stream, knn, mask, flag, fillptr, col);

  // layer 0
  hipLaunchKernelGGL(k_cvt_x,  dim3(NT_/4),    dim3(256), 0, stream, x, Hb);
  hipLaunchKernelGGL(k_cvt_w,  dim3(256),      dim3(256), 0, stream, W0, Wt);
  hipLaunchKernelGGL(k_gemm_mfma, dim3(NT_/64),dim3(512), 0, stream, Hb, Wt, Ab);
  hipLaunchKernelGGL(k_agg,    dim3(NT_/8),    dim3(256), 0, stream, Ab, rowptr, col, dinv, b0, Bagg, partS, partQ);
  hipLaunchKernelGGL(k_stats,  dim3(1),        dim3(1024),0, stream, partS, partQ, stats);
  hipLaunchKernelGGL(k_norm_bf16, dim3(NP_/1024), dim3(256), 0, stream, Bagg, g0, be0, a0, stats, Hb);

  // layer 1
  hipLaunchKernelGGL(k_cvt_w,  dim3(256),      dim3(256), 0, stream, W1, Wt);
  hipLaunchKernelGGL(k_gemm_mfma, dim3(NT_/64),dim3(512), 0, stream, Hb, Wt, Ab);
  hipLaunchKernelGGL(k_agg,    dim3(NT_/8),    dim3(256), 0, stream, Ab, rowptr, col, dinv, b1, Bagg, partS, partQ);
  hipLaunchKernelGGL(k_stats,  dim3(1),        dim3(1024),0, stream, partS, partQ, stats);
  hipLaunchKernelGGL(k_norm_f32,  dim3(NP_/1024), dim3(256), 0, stream, Bagg, g1, be1, a1, stats, out);
}

// Round 5
// 213.943 us; speedup vs baseline: 4.0074x; 1.0970x over previous
//
#include <hip/hip_runtime.h>
#include <hip/hip_bf16.h>
#include <stdint.h>

#define B_   8
#define N_   4096
#define K1_  17
#define D_   256
#define NT_  (B_*N_)          // 32768
#define E16_ (NT_*16)         // 524288
#define NP_  (NT_*D_)         // 8388608
#define EPS_ 1e-5f

typedef __attribute__((ext_vector_type(8))) short short8v;  // 8 bf16 (4 VGPR)
typedef __attribute__((ext_vector_type(4))) short short4v;
typedef __attribute__((ext_vector_type(4))) float f32x4;

// f32 -> bf16 RNE, pure C (verified rounds 1-3; m240: compiler codegen beats asm)
__device__ __forceinline__ unsigned short f2bfu(float f){
  unsigned u = __float_as_uint(f);
  unsigned r = (u + 0x7FFFu + ((u>>16)&1u)) >> 16;
  return (unsigned short)r;
}
__device__ __forceinline__ short f2bf(float f){ return (short)f2bfu(f); }
__device__ __forceinline__ unsigned pkbf(float lo, float hi){
  return (unsigned)f2bfu(lo) | ((unsigned)f2bfu(hi) << 16);
}
__device__ __forceinline__ float bf2f(short s){
  return __uint_as_float(((unsigned)(unsigned short)s) << 16);
}

// ---------------- edge-structure kernels ----------------

// zero degcnt (all blocks) + detect mask storage (block 0):
// flag: 0 = int32 {0,1}, 1 = float32 {0.f,1.f}, 2 = uint8/bool
__global__ __launch_bounds__(256) void k_init(int* __restrict__ degcnt,
                                              const unsigned int* __restrict__ mw,
                                              int* __restrict__ flag){
  int i = blockIdx.x*256 + threadIdx.x;
  degcnt[i] = 0;
  if (blockIdx.x == 0){
    __shared__ int s_int, s_f32;
    if (threadIdx.x==0){ s_int=1; s_f32=1; }
    __syncthreads();
    int bad_i=0, bad_f=0;
    #pragma unroll
    for (int j=0;j<4;j++){
      unsigned w = mw[threadIdx.x*4 + j];
      if (!(w==0u || w==1u))          bad_i=1;
      if (!(w==0u || w==0x3F800000u)) bad_f=1;
    }
    if (bad_i) atomicAnd(&s_int, 0);
    if (bad_f) atomicAnd(&s_f32, 0);
    __syncthreads();
    if (threadIdx.x==0) *flag = s_int ? 0 : (s_f32 ? 1 : 2);
  }
}

__device__ __forceinline__ bool mask_at(const void* maskp, int f, int idx){
  if (f==0) return ((const int*)maskp)[idx] != 0;
  if (f==1) return ((const float*)maskp)[idx] != 0.0f;
  return ((const unsigned char*)maskp)[idx] != 0;
}

__global__ void k_deg(const int* __restrict__ knn, const void* __restrict__ maskp,
                      const int* __restrict__ flag, int* __restrict__ degcnt){
  int f = *flag;
  int e = blockIdx.x*blockDim.x + threadIdx.x;
  if (e >= E16_) return;
  int node = e >> 4;            // b*N + n
  int k    = (e & 15) + 1;      // skip k=0
  int idx  = node*K1_ + k;
  if (mask_at(maskp, f, idx)){
    int b   = node >> 12;
    int dst = knn[idx] + (b<<12);
    atomicAdd(&degcnt[dst], 1);
  }
}

__global__ void k_scan(const int* __restrict__ degcnt, int* __restrict__ rowptr,
                       int* __restrict__ fillptr, float* __restrict__ dinv){
  __shared__ int sm[1024];
  int t = threadIdx.x;
  int base = t*32;
  int loc[32]; int tot = 0;
  #pragma unroll
  for (int i=0;i<32;i++){ loc[i] = degcnt[base+i]; tot += loc[i]; }
  sm[t] = tot; __syncthreads();
  for (int off=1; off<1024; off<<=1){
    int v = (t>=off) ? sm[t-off] : 0;
    __syncthreads();
    sm[t] += v;
    __syncthreads();
  }
  int run = sm[t] - tot;
  #pragma unroll
  for (int i=0;i<32;i++){
    int v = base+i;
    rowptr[v]  = run;
    fillptr[v] = run;
    dinv[v]    = rsqrtf((float)loc[i] + 1.0f);
    run += loc[i];
  }
  if (t==1023) rowptr[NT_] = run;
}

__global__ void k_fill(const int* __restrict__ knn, const void* __restrict__ maskp,
                       const int* __restrict__ flag, int* __restrict__ fillptr,
                       int* __restrict__ col){
  int f = *flag;
  int e = blockIdx.x*blockDim.x + threadIdx.x;
  if (e >= E16_) return;
  int node = e >> 4;
  int k    = (e & 15) + 1;
  int idx  = node*K1_ + k;
  if (mask_at(maskp, f, idx)){
    int b   = node >> 12;
    int dst = knn[idx] + (b<<12);
    int pos = atomicAdd(&fillptr[dst], 1);
    col[pos] = node;
  }
}

// ---------------- weight transpose (both layers, LDS-tiled) ----------------
// 128 blocks: even -> W0, odd -> W1; tile = 32x32. Wt[n][k] = bf16(W[k][n]).
__global__ __launch_bounds__(256) void k_cvt_w(const float* __restrict__ W0,
                                               const float* __restrict__ W1,
                                               short* __restrict__ Wt0,
                                               short* __restrict__ Wt1){
  const float* W  = (blockIdx.x & 1) ? W1  : W0;
  short*       Wt = (blockIdx.x & 1) ? Wt1 : Wt0;
  int tile = blockIdx.x >> 1;
  int ti = tile >> 3, tj = tile & 7;      // ti: k-tile, tj: n-tile
  __shared__ float sm[32][33];
  int r = threadIdx.x >> 5, c = threadIdx.x & 31;
  #pragma unroll
  for (int i=0;i<4;i++)
    sm[r + i*8][c] = W[(ti*32 + r + i*8)*256 + tj*32 + c];
  __syncthreads();
  #pragma unroll
  for (int i=0;i<4;i++){
    int rr = r + i*8;
    Wt[(size_t)(tj*32 + rr)*256 + ti*32 + c] = f2bf(sm[c][rr]);
  }
}

// ---------------- MFMA GEMM, B-resident-in-registers ----------------
// 512 thr = 8 waves; wave w owns col strips {2w,2w+1}. 64 rows per block.
// A frag: lane l holds row row0+(l&15), elems ks*32 + 8*(l>>4) + j
// B frag: lane l holds Wt[strip*16+(l&15)][ks*32 + 8*(l>>4) + j]
// D frag: lane l reg r -> D[row0 + 4*(l>>4)+r][strip*16 + (l&15)]

// layer 0: A read from x (f32, row stride 512), converted in-register
__global__ __launch_bounds__(512) void k_gemm_x(const float* __restrict__ X,
                                                const short* __restrict__ Wt,
                                                short* __restrict__ Ab){
  int wave = threadIdx.x >> 6;
  int lane = threadIdx.x & 63;
  int lr   = lane & 15;
  int lk   = (lane >> 4) * 8;
  int s0   = wave*2, s1 = wave*2 + 1;

  short8v b0[8], b1[8];
  const short* w0p = Wt + (size_t)(s0*16 + lr)*256 + lk;
  const short* w1p = Wt + (size_t)(s1*16 + lr)*256 + lk;
  #pragma unroll
  for (int ks=0; ks<8; ks++){
    b0[ks] = *(const short8v*)(w0p + ks*32);
    b1[ks] = *(const short8v*)(w1p + ks*32);
  }

  int rowB = blockIdx.x*64;
  #pragma unroll
  for (int rt=0; rt<4; rt++){
    int row0 = rowB + rt*16;
    const float* aRow = X + (size_t)(row0 + lr)*512 + lk;
    f32x4 acc0 = (f32x4){0.f,0.f,0.f,0.f};
    f32x4 acc1 = (f32x4){0.f,0.f,0.f,0.f};
    #pragma unroll
    for (int ks=0; ks<8; ks++){
      f32x4 p0 = *(const f32x4*)(aRow + ks*32);
      f32x4 p1 = *(const f32x4*)(aRow + ks*32 + 4);
      union { unsigned u[4]; short8v v; } cv;
      cv.u[0] = pkbf(p0[0], p0[1]);
      cv.u[1] = pkbf(p0[2], p0[3]);
      cv.u[2] = pkbf(p1[0], p1[1]);
      cv.u[3] = pkbf(p1[2], p1[3]);
      acc0 = __builtin_amdgcn_mfma_f32_16x16x32_bf16(cv.v, b0[ks], acc0, 0, 0, 0);
      acc1 = __builtin_amdgcn_mfma_f32_16x16x32_bf16(cv.v, b1[ks], acc1, 0, 0, 0);
    }
    int mrow = row0 + (lane>>4)*4;
    #pragma unroll
    for (int r=0;r<4;r++){
      Ab[(size_t)(mrow + r)*256 + s0*16 + lr] = f2bf(acc0[r]);
      Ab[(size_t)(mrow + r)*256 + s1*16 + lr] = f2bf(acc1[r]);
    }
  }
}

// layer 1: A read from Hb (bf16, row stride 256)
__global__ __launch_bounds__(512) void k_gemm_h(const short* __restrict__ Hb,
                                                const short* __restrict__ Wt,
                                                short* __restrict__ Ab){
  int wave = threadIdx.x >> 6;
  int lane = threadIdx.x & 63;
  int lr   = lane & 15;
  int lk   = (lane >> 4) * 8;
  int s0   = wave*2, s1 = wave*2 + 1;

  short8v b0[8], b1[8];
  const short* w0p = Wt + (size_t)(s0*16 + lr)*256 + lk;
  const short* w1p = Wt + (size_t)(s1*16 + lr)*256 + lk;
  #pragma unroll
  for (int ks=0; ks<8; ks++){
    b0[ks] = *(const short8v*)(w0p + ks*32);
    b1[ks] = *(const short8v*)(w1p + ks*32);
  }

  int rowB = blockIdx.x*64;
  #pragma unroll
  for (int rt=0; rt<4; rt++){
    int row0 = rowB + rt*16;
    const short* aRow = Hb + (size_t)(row0 + lr)*256 + lk;
    f32x4 acc0 = (f32x4){0.f,0.f,0.f,0.f};
    f32x4 acc1 = (f32x4){0.f,0.f,0.f,0.f};
    #pragma unroll
    for (int ks=0; ks<8; ks++){
      short8v a = *(const short8v*)(aRow + ks*32);
      acc0 = __builtin_amdgcn_mfma_f32_16x16x32_bf16(a, b0[ks], acc0, 0, 0, 0);
      acc1 = __builtin_amdgcn_mfma_f32_16x16x32_bf16(a, b1[ks], acc1, 0, 0, 0);
    }
    int mrow = row0 + (lane>>4)*4;
    #pragma unroll
    for (int r=0;r<4;r++){
      Ab[(size_t)(mrow + r)*256 + s0*16 + lr] = f2bf(acc0[r]);
      Ab[(size_t)(mrow + r)*256 + s1*16 + lr] = f2bf(acc1[r]);
    }
  }
}

// ---------------- aggregation: 32 lanes/node, XCD-swizzled, bf16 out ----------------
// 4096 blocks; swizzle so XCD x gets contiguous blocks = one batch (2MB, L2-fit).
// Per-block stats partials (8-node LDS reduce).
__global__ __launch_bounds__(256) void k_agg(const short* __restrict__ Ab,
    const int* __restrict__ rowptr, const int* __restrict__ col,
    const float* __restrict__ dinv, const float* __restrict__ bvec,
    unsigned* __restrict__ outU, float* __restrict__ partS, float* __restrict__ partQ){
  int bid  = (int)(blockIdx.x & 7) * 512 + (int)(blockIdx.x >> 3);  // XCD swizzle
  int node = bid*8 + (threadIdx.x >> 5);
  int sub  = threadIdx.x & 31;
  int c0   = sub*8;
  float dv = dinv[node];

  float acc[8];
  {
    short8v s = *(const short8v*)&Ab[(size_t)node*256 + c0];
    #pragma unroll
    for (int i=0;i<8;i++) acc[i] = dv * bf2f(s[i]);
  }
  int j0 = rowptr[node], j1 = rowptr[node+1];
  for (int j=j0;j<j1;j++){
    int s = col[j];
    float ds = dinv[s];
    short8v nb = *(const short8v*)&Ab[(size_t)s*256 + c0];
    #pragma unroll
    for (int i=0;i<8;i++) acc[i] += ds * bf2f(nb[i]);
  }
  float sum=0.f, sq=0.f;
  float o[8];
  #pragma unroll
  for (int i=0;i<8;i++){
    float v = dv*acc[i] + bvec[c0+i];
    o[i] = v;
    sum += v; sq += v*v;
  }
  uint4 ov;
  ov.x = pkbf(o[0],o[1]); ov.y = pkbf(o[2],o[3]);
  ov.z = pkbf(o[4],o[5]); ov.w = pkbf(o[6],o[7]);
  *(uint4*)&outU[(size_t)node*128 + sub*4] = ov;

  #pragma unroll
  for (int off=16; off>0; off>>=1){
    sum += __shfl_down(sum, off, 32);
    sq  += __shfl_down(sq,  off, 32);
  }
  __shared__ float ls1[8], ls2[8];
  if (sub==0){ ls1[threadIdx.x>>5]=sum; ls2[threadIdx.x>>5]=sq; }
  __syncthreads();
  if (threadIdx.x==0){
    float a=0.f, b=0.f;
    #pragma unroll
    for (int i=0;i<8;i++){ a+=ls1[i]; b+=ls2[i]; }
    partS[bid]=a; partQ[bid]=b;
  }
}

// ---------------- stats over 4096 per-block partials (double accum) ----------------
__global__ void k_stats(const float* __restrict__ partS, const float* __restrict__ partQ,
                        float* __restrict__ stats){
  __shared__ double s1[1024], s2[1024];
  int t = threadIdx.x;
  double a=0.0, b=0.0;
  for (int i=t; i<4096; i+=1024){ a += (double)partS[i]; b += (double)partQ[i]; }
  s1[t]=a; s2[t]=b; __syncthreads();
  for (int off=512; off>0; off>>=1){
    if (t<off){ s1[t]+=s1[t+off]; s2[t]+=s2[t+off]; }
    __syncthreads();
  }
  if (t==0){
    double mean = s1[0] / (double)NP_;
    double var  = s2[0] / (double)NP_ - mean*mean;
    var = var > 0.0 ? var : 0.0;
    stats[0] = (float)mean;
    stats[1] = (float)(1.0 / (sqrt(var) + (double)EPS_));
  }
}

// ---------------- norm + prelu (bf16 in; bf16 or f32 out), 8 elems/thread ----------------
__device__ __forceinline__ void unpack2(unsigned u, float& lo, float& hi){
  lo = __uint_as_float(u << 16);
  hi = __uint_as_float(u & 0xFFFF0000u);
}

__global__ __launch_bounds__(256) void k_norm_bf16(const unsigned* __restrict__ inU,
    const float* __restrict__ g, const float* __restrict__ be,
    const float* __restrict__ aP, const float* __restrict__ stats,
    unsigned* __restrict__ outU){
  float mean = stats[0], inv = stats[1], a = aP[0];
  int gid   = blockIdx.x*256 + threadIdx.x;
  int base8 = gid*8;
  int c0    = base8 & (D_-1);
  uint4 vin = *(const uint4*)&inU[gid*4];
  float4 g0 = *(const float4*)&g[c0],  g1 = *(const float4*)&g[c0+4];
  float4 e0 = *(const float4*)&be[c0], e1 = *(const float4*)&be[c0+4];
  float v[8];
  unpack2(vin.x, v[0], v[1]); unpack2(vin.y, v[2], v[3]);
  unpack2(vin.z, v[4], v[5]); unpack2(vin.w, v[6], v[7]);
  float gg[8] = {g0.x,g0.y,g0.z,g0.w,g1.x,g1.y,g1.z,g1.w};
  float eb[8] = {e0.x,e0.y,e0.z,e0.w,e1.x,e1.y,e1.z,e1.w};
  float o[8];
  #pragma unroll
  for (int i=0;i<8;i++){
    float t = gg[i]*((v[i]-mean)*inv) + eb[i];
    o[i] = t>=0.f ? t : a*t;
  }
  uint4 ov;
  ov.x = pkbf(o[0],o[1]); ov.y = pkbf(o[2],o[3]);
  ov.z = pkbf(o[4],o[5]); ov.w = pkbf(o[6],o[7]);
  *(uint4*)&outU[gid*4] = ov;
}

__global__ __launch_bounds__(256) void k_norm_f32(const unsigned* __restrict__ inU,
    const float* __restrict__ g, const float* __restrict__ be,
    const float* __restrict__ aP, const float* __restrict__ stats,
    float* __restrict__ out){
  float mean = stats[0], inv = stats[1], a = aP[0];
  int gid   = blockIdx.x*256 + threadIdx.x;
  int base8 = gid*8;
  int c0    = base8 & (D_-1);
  uint4 vin = *(const uint4*)&inU[gid*4];
  float4 g0 = *(const float4*)&g[c0],  g1 = *(const float4*)&g[c0+4];
  float4 e0 = *(const float4*)&be[c0], e1 = *(const float4*)&be[c0+4];
  float v[8];
  unpack2(vin.x, v[0], v[1]); unpack2(vin.y, v[2], v[3]);
  unpack2(vin.z, v[4], v[5]); unpack2(vin.w, v[6], v[7]);
  float gg[8] = {g0.x,g0.y,g0.z,g0.w,g1.x,g1.y,g1.z,g1.w};
  float eb[8] = {e0.x,e0.y,e0.z,e0.w,e1.x,e1.y,e1.z,e1.w};
  f32x4 o0, o1;
  #pragma unroll
  for (int i=0;i<8;i++){
    float t = gg[i]*((v[i]-mean)*inv) + eb[i];
    t = t>=0.f ? t : a*t;
    if (i<4) o0[i] = t; else o1[i-4] = t;
  }
  *(f32x4*)&out[base8]     = o0;
  *(f32x4*)&out[base8 + 4] = o1;
}

// ---------------- launch ----------------

extern "C" void kernel_launch(void* const* d_in, const int* in_sizes, int n_in,
                              void* d_out, int out_size, void* d_ws, size_t ws_size,
                              hipStream_t stream){
  const float* x    = (const float*)d_in[0];
  const int*   knn  = (const int*)  d_in[1];
  const void*  mask =               d_in[2];
  const float* W0   = (const float*)d_in[3];
  const float* b0   = (const float*)d_in[4];
  const float* g0   = (const float*)d_in[5];
  const float* be0  = (const float*)d_in[6];
  const float* a0   = (const float*)d_in[7];
  const float* W1   = (const float*)d_in[8];
  const float* b1   = (const float*)d_in[9];
  const float* g1   = (const float*)d_in[10];
  const float* be1  = (const float*)d_in[11];
  const float* a1   = (const float*)d_in[12];
  float* out = (float*)d_out;

  char* w = (char*)d_ws;
  size_t off = 0;
  auto alloc = [&](size_t bytes)->void*{
    void* p = w + off; off = (off + bytes + 255) & ~(size_t)255; return p;
  };
  int*      degcnt  = (int*)     alloc(NT_*4);
  int*      rowptr  = (int*)     alloc((NT_+1)*4);
  int*      fillptr = (int*)     alloc(NT_*4);
  int*      col     = (int*)     alloc(E16_*4);
  float*    dinv    = (float*)   alloc(NT_*4);
  float*    partS   = (float*)   alloc(4096*4);
  float*    partQ   = (float*)   alloc(4096*4);
  float*    stats   = (float*)   alloc(4*4);
  int*      flag    = (int*)     alloc(4);
  short*    Hb      = (short*)   alloc((size_t)NP_*2);   // layer-1 input (bf16)
  short*    Ab      = (short*)   alloc((size_t)NP_*2);   // gemm output (bf16)
  unsigned* Bagg    = (unsigned*)alloc((size_t)NP_*2);   // agg output (bf16 pairs)
  short*    Wt0     = (short*)   alloc(256*256*2);
  short*    Wt1     = (short*)   alloc(256*256*2);

  // edge structure + weights
  hipLaunchKernelGGL(k_init,  dim3(NT_/256),  dim3(256), 0, stream, degcnt, (const unsigned int*)mask, flag);
  hipLaunchKernelGGL(k_deg,   dim3(E16_/256), dim3(256), 0, stream, knn, mask, flag, degcnt);
  hipLaunchKernelGGL(k_scan,  dim3(1),        dim3(1024),0, stream, degcnt, rowptr, fillptr, dinv);
  hipLaunchKernelGGL(k_fill,  dim3(E16_/256), dim3(256), 0, stream, knn, mask, flag, fillptr, col);
  hipLaunchKernelGGL(k_cvt_w, dim3(128),      dim3(256), 0, stream, W0, W1, Wt0, Wt1);

  // layer 0
  hipLaunchKernelGGL(k_gemm_x, dim3(NT_/64),  dim3(512), 0, stream, x, Wt0, Ab);
  hipLaunchKernelGGL(k_agg,    dim3(NT_/8),   dim3(256), 0, stream, Ab, rowptr, col, dinv, b0, Bagg, partS, partQ);
  hipLaunchKernelGGL(k_stats,  dim3(1),       dim3(1024),0, stream, partS, partQ, stats);
  hipLaunchKernelGGL(k_norm_bf16, dim3(NP_/2048), dim3(256), 0, stream, Bagg, g0, be0, a0, stats, (unsigned*)Hb);

  // layer 1
  hipLaunchKernelGGL(k_gemm_h, dim3(NT_/64),  dim3(512), 0, stream, Hb, Wt1, Ab);
  hipLaunchKernelGGL(k_agg,    dim3(NT_/8),   dim3(256), 0, stream, Ab, rowptr, col, dinv, b1, Bagg, partS, partQ);
  hipLaunchKernelGGL(k_stats,  dim3(1),       dim3(1024),0, stream, partS, partQ, stats);
  hipLaunchKernelGGL(k_norm_f32,  dim3(NP_/2048), dim3(256), 0, stream, Bagg, g1, be1, a1, stats, out);
}

// Round 6
// 212.551 us; speedup vs baseline: 4.0336x; 1.0066x over previous
//
#include <hip/hip_runtime.h>
#include <hip/hip_bf16.h>
#include <stdint.h>

#define B_   8
#define N_   4096
#define K1_  17
#define D_   256
#define NT_  (B_*N_)          // 32768
#define E16_ (NT_*16)         // 524288
#define NP_  (NT_*D_)         // 8388608
#define EPS_ 1e-5f

typedef __attribute__((ext_vector_type(8))) short short8v;  // 8 bf16 (4 VGPR)
typedef __attribute__((ext_vector_type(4))) short short4v;
typedef __attribute__((ext_vector_type(4))) float f32x4;

// f32 -> bf16 RNE, pure C (verified rounds 1-3; m240: compiler codegen beats asm)
__device__ __forceinline__ unsigned short f2bfu(float f){
  unsigned u = __float_as_uint(f);
  unsigned r = (u + 0x7FFFu + ((u>>16)&1u)) >> 16;
  return (unsigned short)r;
}
__device__ __forceinline__ short f2bf(float f){ return (short)f2bfu(f); }
__device__ __forceinline__ unsigned pkbf(float lo, float hi){
  return (unsigned)f2bfu(lo) | ((unsigned)f2bfu(hi) << 16);
}
__device__ __forceinline__ float bf2f(short s){
  return __uint_as_float(((unsigned)(unsigned short)s) << 16);
}

// ---------------- edge-structure kernels ----------------

// zero degcnt (all blocks) + detect mask storage (block 0):
// flag: 0 = int32 {0,1}, 1 = float32 {0.f,1.f}, 2 = uint8/bool
__global__ __launch_bounds__(256) void k_init(int* __restrict__ degcnt,
                                              const unsigned int* __restrict__ mw,
                                              int* __restrict__ flag){
  int i = blockIdx.x*256 + threadIdx.x;
  degcnt[i] = 0;
  if (blockIdx.x == 0){
    __shared__ int s_int, s_f32;
    if (threadIdx.x==0){ s_int=1; s_f32=1; }
    __syncthreads();
    int bad_i=0, bad_f=0;
    #pragma unroll
    for (int j=0;j<4;j++){
      unsigned w = mw[threadIdx.x*4 + j];
      if (!(w==0u || w==1u))          bad_i=1;
      if (!(w==0u || w==0x3F800000u)) bad_f=1;
    }
    if (bad_i) atomicAnd(&s_int, 0);
    if (bad_f) atomicAnd(&s_f32, 0);
    __syncthreads();
    if (threadIdx.x==0) *flag = s_int ? 0 : (s_f32 ? 1 : 2);
  }
}

__device__ __forceinline__ bool mask_at(const void* maskp, int f, int idx){
  if (f==0) return ((const int*)maskp)[idx] != 0;
  if (f==1) return ((const float*)maskp)[idx] != 0.0f;
  return ((const unsigned char*)maskp)[idx] != 0;
}

__global__ void k_deg(const int* __restrict__ knn, const void* __restrict__ maskp,
                      const int* __restrict__ flag, int* __restrict__ degcnt){
  int f = *flag;
  int e = blockIdx.x*blockDim.x + threadIdx.x;
  if (e >= E16_) return;
  int node = e >> 4;            // b*N + n
  int k    = (e & 15) + 1;      // skip k=0
  int idx  = node*K1_ + k;
  if (mask_at(maskp, f, idx)){
    int b   = node >> 12;
    int dst = knn[idx] + (b<<12);
    atomicAdd(&degcnt[dst], 1);
  }
}

__global__ void k_scan(const int* __restrict__ degcnt, int* __restrict__ rowptr,
                       int* __restrict__ fillptr, float* __restrict__ dinv){
  __shared__ int sm[1024];
  int t = threadIdx.x;
  int base = t*32;
  int loc[32]; int tot = 0;
  #pragma unroll
  for (int i=0;i<32;i++){ loc[i] = degcnt[base+i]; tot += loc[i]; }
  sm[t] = tot; __syncthreads();
  for (int off=1; off<1024; off<<=1){
    int v = (t>=off) ? sm[t-off] : 0;
    __syncthreads();
    sm[t] += v;
    __syncthreads();
  }
  int run = sm[t] - tot;
  #pragma unroll
  for (int i=0;i<32;i++){
    int v = base+i;
    rowptr[v]  = run;
    fillptr[v] = run;
    dinv[v]    = rsqrtf((float)loc[i] + 1.0f);
    run += loc[i];
  }
  if (t==1023) rowptr[NT_] = run;
}

__global__ void k_fill(const int* __restrict__ knn, const void* __restrict__ maskp,
                       const int* __restrict__ flag, int* __restrict__ fillptr,
                       int* __restrict__ col){
  int f = *flag;
  int e = blockIdx.x*blockDim.x + threadIdx.x;
  if (e >= E16_) return;
  int node = e >> 4;
  int k    = (e & 15) + 1;
  int idx  = node*K1_ + k;
  if (mask_at(maskp, f, idx)){
    int b   = node >> 12;
    int dst = knn[idx] + (b<<12);
    int pos = atomicAdd(&fillptr[dst], 1);
    col[pos] = node;
  }
}

// ---------------- weight transpose (both layers, LDS-tiled) ----------------
// 128 blocks: even -> W0, odd -> W1; tile = 32x32. Wt[n][k] = bf16(W[k][n]).
__global__ __launch_bounds__(256) void k_cvt_w(const float* __restrict__ W0,
                                               const float* __restrict__ W1,
                                               short* __restrict__ Wt0,
                                               short* __restrict__ Wt1){
  const float* W  = (blockIdx.x & 1) ? W1  : W0;
  short*       Wt = (blockIdx.x & 1) ? Wt1 : Wt0;
  int tile = blockIdx.x >> 1;
  int ti = tile >> 3, tj = tile & 7;      // ti: k-tile, tj: n-tile
  __shared__ float sm[32][33];
  int r = threadIdx.x >> 5, c = threadIdx.x & 31;
  #pragma unroll
  for (int i=0;i<4;i++)
    sm[r + i*8][c] = W[(ti*32 + r + i*8)*256 + tj*32 + c];
  __syncthreads();
  #pragma unroll
  for (int i=0;i<4;i++){
    int rr = r + i*8;
    Wt[(size_t)(tj*32 + rr)*256 + ti*32 + c] = f2bf(sm[c][rr]);
  }
}

// ---------------- MFMA GEMM, B-resident-in-registers ----------------
// 512 thr = 8 waves; wave w owns col strips {2w,2w+1}. 64 rows per block.
// __launch_bounds__(512,4): VGPR cap 128 (2 blocks/CU) -- enough to keep the
// 16 B-frags (64 VGPR) + 2 acc (8) resident. Without this the compiler caps
// at 44 VGPR and re-loads B every row-tile (round-5: 44us, MfmaUtil 3.4%).
// XCD swizzle: grid 512, XCD x gets 64 contiguous blocks = batch x.
// A frag: lane l holds row row0+(l&15), elems ks*32 + 8*(l>>4) + j
// B frag: lane l holds Wt[strip*16+(l&15)][ks*32 + 8*(l>>4) + j]
// D frag: lane l reg r -> D[row0 + 4*(l>>4)+r][strip*16 + (l&15)]

// layer 0: A read from x (f32, row stride 512), converted in-register
__global__ __launch_bounds__(512, 4) void k_gemm_x(const float* __restrict__ X,
                                                   const short* __restrict__ Wt,
                                                   short* __restrict__ Ab){
  int bid  = (int)(blockIdx.x & 7) * 64 + (int)(blockIdx.x >> 3);  // XCD swizzle
  int wave = threadIdx.x >> 6;
  int lane = threadIdx.x & 63;
  int lr   = lane & 15;
  int lk   = (lane >> 4) * 8;
  int s0   = wave*2, s1 = wave*2 + 1;

  short8v b0[8], b1[8];
  const short* w0p = Wt + (size_t)(s0*16 + lr)*256 + lk;
  const short* w1p = Wt + (size_t)(s1*16 + lr)*256 + lk;
  #pragma unroll
  for (int ks=0; ks<8; ks++){
    b0[ks] = *(const short8v*)(w0p + ks*32);
    b1[ks] = *(const short8v*)(w1p + ks*32);
  }

  int rowB = bid*64;
  #pragma unroll
  for (int rt=0; rt<4; rt++){
    int row0 = rowB + rt*16;
    const float* aRow = X + (size_t)(row0 + lr)*512 + lk;
    f32x4 acc0 = (f32x4){0.f,0.f,0.f,0.f};
    f32x4 acc1 = (f32x4){0.f,0.f,0.f,0.f};
    #pragma unroll
    for (int ks=0; ks<8; ks++){
      f32x4 p0 = *(const f32x4*)(aRow + ks*32);
      f32x4 p1 = *(const f32x4*)(aRow + ks*32 + 4);
      union { unsigned u[4]; short8v v; } cv;
      cv.u[0] = pkbf(p0[0], p0[1]);
      cv.u[1] = pkbf(p0[2], p0[3]);
      cv.u[2] = pkbf(p1[0], p1[1]);
      cv.u[3] = pkbf(p1[2], p1[3]);
      acc0 = __builtin_amdgcn_mfma_f32_16x16x32_bf16(cv.v, b0[ks], acc0, 0, 0, 0);
      acc1 = __builtin_amdgcn_mfma_f32_16x16x32_bf16(cv.v, b1[ks], acc1, 0, 0, 0);
    }
    int mrow = row0 + (lane>>4)*4;
    #pragma unroll
    for (int r=0;r<4;r++){
      Ab[(size_t)(mrow + r)*256 + s0*16 + lr] = f2bf(acc0[r]);
      Ab[(size_t)(mrow + r)*256 + s1*16 + lr] = f2bf(acc1[r]);
    }
  }
}

// layer 1: A read from Hb (bf16, row stride 256)
__global__ __launch_bounds__(512, 4) void k_gemm_h(const short* __restrict__ Hb,
                                                   const short* __restrict__ Wt,
                                                   short* __restrict__ Ab){
  int bid  = (int)(blockIdx.x & 7) * 64 + (int)(blockIdx.x >> 3);  // XCD swizzle
  int wave = threadIdx.x >> 6;
  int lane = threadIdx.x & 63;
  int lr   = lane & 15;
  int lk   = (lane >> 4) * 8;
  int s0   = wave*2, s1 = wave*2 + 1;

  short8v b0[8], b1[8];
  const short* w0p = Wt + (size_t)(s0*16 + lr)*256 + lk;
  const short* w1p = Wt + (size_t)(s1*16 + lr)*256 + lk;
  #pragma unroll
  for (int ks=0; ks<8; ks++){
    b0[ks] = *(const short8v*)(w0p + ks*32);
    b1[ks] = *(const short8v*)(w1p + ks*32);
  }

  int rowB = bid*64;
  #pragma unroll
  for (int rt=0; rt<4; rt++){
    int row0 = rowB + rt*16;
    const short* aRow = Hb + (size_t)(row0 + lr)*256 + lk;
    f32x4 acc0 = (f32x4){0.f,0.f,0.f,0.f};
    f32x4 acc1 = (f32x4){0.f,0.f,0.f,0.f};
    #pragma unroll
    for (int ks=0; ks<8; ks++){
      short8v a = *(const short8v*)(aRow + ks*32);
      acc0 = __builtin_amdgcn_mfma_f32_16x16x32_bf16(a, b0[ks], acc0, 0, 0, 0);
      acc1 = __builtin_amdgcn_mfma_f32_16x16x32_bf16(a, b1[ks], acc1, 0, 0, 0);
    }
    int mrow = row0 + (lane>>4)*4;
    #pragma unroll
    for (int r=0;r<4;r++){
      Ab[(size_t)(mrow + r)*256 + s0*16 + lr] = f2bf(acc0[r]);
      Ab[(size_t)(mrow + r)*256 + s1*16 + lr] = f2bf(acc1[r]);
    }
  }
}

// ---------------- aggregation: 32 lanes/node, XCD-swizzled, bf16 out ----------------
// 4096 blocks; swizzle so XCD x gets contiguous blocks = one batch (2MB, L2-fit).
// Per-block stats partials (8-node LDS reduce).
__global__ __launch_bounds__(256) void k_agg(const short* __restrict__ Ab,
    const int* __restrict__ rowptr, const int* __restrict__ col,
    const float* __restrict__ dinv, const float* __restrict__ bvec,
    unsigned* __restrict__ outU, float* __restrict__ partS, float* __restrict__ partQ){
  int bid  = (int)(blockIdx.x & 7) * 512 + (int)(blockIdx.x >> 3);  // XCD swizzle
  int node = bid*8 + (threadIdx.x >> 5);
  int sub  = threadIdx.x & 31;
  int c0   = sub*8;
  float dv = dinv[node];

  float acc[8];
  {
    short8v s = *(const short8v*)&Ab[(size_t)node*256 + c0];
    #pragma unroll
    for (int i=0;i<8;i++) acc[i] = dv * bf2f(s[i]);
  }
  int j0 = rowptr[node], j1 = rowptr[node+1];
  for (int j=j0;j<j1;j++){
    int s = col[j];
    float ds = dinv[s];
    short8v nb = *(const short8v*)&Ab[(size_t)s*256 + c0];
    #pragma unroll
    for (int i=0;i<8;i++) acc[i] += ds * bf2f(nb[i]);
  }
  float sum=0.f, sq=0.f;
  float o[8];
  #pragma unroll
  for (int i=0;i<8;i++){
    float v = dv*acc[i] + bvec[c0+i];
    o[i] = v;
    sum += v; sq += v*v;
  }
  uint4 ov;
  ov.x = pkbf(o[0],o[1]); ov.y = pkbf(o[2],o[3]);
  ov.z = pkbf(o[4],o[5]); ov.w = pkbf(o[6],o[7]);
  *(uint4*)&outU[(size_t)node*128 + sub*4] = ov;

  #pragma unroll
  for (int off=16; off>0; off>>=1){
    sum += __shfl_down(sum, off, 32);
    sq  += __shfl_down(sq,  off, 32);
  }
  __shared__ float ls1[8], ls2[8];
  if (sub==0){ ls1[threadIdx.x>>5]=sum; ls2[threadIdx.x>>5]=sq; }
  __syncthreads();
  if (threadIdx.x==0){
    float a=0.f, b=0.f;
    #pragma unroll
    for (int i=0;i<8;i++){ a+=ls1[i]; b+=ls2[i]; }
    partS[bid]=a; partQ[bid]=b;
  }
}

// ---------------- stats over 4096 per-block partials (double accum) ----------------
__global__ void k_stats(const float* __restrict__ partS, const float* __restrict__ partQ,
                        float* __restrict__ stats){
  __shared__ double s1[1024], s2[1024];
  int t = threadIdx.x;
  double a=0.0, b=0.0;
  for (int i=t; i<4096; i+=1024){ a += (double)partS[i]; b += (double)partQ[i]; }
  s1[t]=a; s2[t]=b; __syncthreads();
  for (int off=512; off>0; off>>=1){
    if (t<off){ s1[t]+=s1[t+off]; s2[t]+=s2[t+off]; }
    __syncthreads();
  }
  if (t==0){
    double mean = s1[0] / (double)NP_;
    double var  = s2[0] / (double)NP_ - mean*mean;
    var = var > 0.0 ? var : 0.0;
    stats[0] = (float)mean;
    stats[1] = (float)(1.0 / (sqrt(var) + (double)EPS_));
  }
}

// ---------------- norm + prelu (bf16 in; bf16 or f32 out), 8 elems/thread ----------------
__device__ __forceinline__ void unpack2(unsigned u, float& lo, float& hi){
  lo = __uint_as_float(u << 16);
  hi = __uint_as_float(u & 0xFFFF0000u);
}

__global__ __launch_bounds__(256) void k_norm_bf16(const unsigned* __restrict__ inU,
    const float* __restrict__ g, const float* __restrict__ be,
    const float* __restrict__ aP, const float* __restrict__ stats,
    unsigned* __restrict__ outU){
  float mean = stats[0], inv = stats[1], a = aP[0];
  int gid   = blockIdx.x*256 + threadIdx.x;
  int base8 = gid*8;
  int c0    = base8 & (D_-1);
  uint4 vin = *(const uint4*)&inU[gid*4];
  float4 g0 = *(const float4*)&g[c0],  g1 = *(const float4*)&g[c0+4];
  float4 e0 = *(const float4*)&be[c0], e1 = *(const float4*)&be[c0+4];
  float v[8];
  unpack2(vin.x, v[0], v[1]); unpack2(vin.y, v[2], v[3]);
  unpack2(vin.z, v[4], v[5]); unpack2(vin.w, v[6], v[7]);
  float gg[8] = {g0.x,g0.y,g0.z,g0.w,g1.x,g1.y,g1.z,g1.w};
  float eb[8] = {e0.x,e0.y,e0.z,e0.w,e1.x,e1.y,e1.z,e1.w};
  float o[8];
  #pragma unroll
  for (int i=0;i<8;i++){
    float t = gg[i]*((v[i]-mean)*inv) + eb[i];
    o[i] = t>=0.f ? t : a*t;
  }
  uint4 ov;
  ov.x = pkbf(o[0],o[1]); ov.y = pkbf(o[2],o[3]);
  ov.z = pkbf(o[4],o[5]); ov.w = pkbf(o[6],o[7]);
  *(uint4*)&outU[gid*4] = ov;
}

__global__ __launch_bounds__(256) void k_norm_f32(const unsigned* __restrict__ inU,
    const float* __restrict__ g, const float* __restrict__ be,
    const float* __restrict__ aP, const float* __restrict__ stats,
    float* __restrict__ out){
  float mean = stats[0], inv = stats[1], a = aP[0];
  int gid   = blockIdx.x*256 + threadIdx.x;
  int base8 = gid*8;
  int c0    = base8 & (D_-1);
  uint4 vin = *(const uint4*)&inU[gid*4];
  float4 g0 = *(const float4*)&g[c0],  g1 = *(const float4*)&g[c0+4];
  float4 e0 = *(const float4*)&be[c0], e1 = *(const float4*)&be[c0+4];
  float v[8];
  unpack2(vin.x, v[0], v[1]); unpack2(vin.y, v[2], v[3]);
  unpack2(vin.z, v[4], v[5]); unpack2(vin.w, v[6], v[7]);
  float gg[8] = {g0.x,g0.y,g0.z,g0.w,g1.x,g1.y,g1.z,g1.w};
  float eb[8] = {e0.x,e0.y,e0.z,e0.w,e1.x,e1.y,e1.z,e1.w};
  f32x4 o0, o1;
  #pragma unroll
  for (int i=0;i<8;i++){
    float t = gg[i]*((v[i]-mean)*inv) + eb[i];
    t = t>=0.f ? t : a*t;
    if (i<4) o0[i] = t; else o1[i-4] = t;
  }
  *(f32x4*)&out[base8]     = o0;
  *(f32x4*)&out[base8 + 4] = o1;
}

// ---------------- launch ----------------

extern "C" void kernel_launch(void* const* d_in, const int* in_sizes, int n_in,
                              void* d_out, int out_size, void* d_ws, size_t ws_size,
                              hipStream_t stream){
  const float* x    = (const float*)d_in[0];
  const int*   knn  = (const int*)  d_in[1];
  const void*  mask =               d_in[2];
  const float* W0   = (const float*)d_in[3];
  const float* b0   = (const float*)d_in[4];
  const float* g0   = (const float*)d_in[5];
  const float* be0  = (const float*)d_in[6];
  const float* a0   = (const float*)d_in[7];
  const float* W1   = (const float*)d_in[8];
  const float* b1   = (const float*)d_in[9];
  const float* g1   = (const float*)d_in[10];
  const float* be1  = (const float*)d_in[11];
  const float* a1   = (const float*)d_in[12];
  float* out = (float*)d_out;

  char* w = (char*)d_ws;
  size_t off = 0;
  auto alloc = [&](size_t bytes)->void*{
    void* p = w + off; off = (off + bytes + 255) & ~(size_t)255; return p;
  };
  int*      degcnt  = (int*)     alloc(NT_*4);
  int*      rowptr  = (int*)     alloc((NT_+1)*4);
  int*      fillptr = (int*)     alloc(NT_*4);
  int*      col     = (int*)     alloc(E16_*4);
  float*    dinv    = (float*)   alloc(NT_*4);
  float*    partS   = (float*)   alloc(4096*4);
  float*    partQ   = (float*)   alloc(4096*4);
  float*    stats   = (float*)   alloc(4*4);
  int*      flag    = (int*)     alloc(4);
  short*    Hb      = (short*)   alloc((size_t)NP_*2);   // layer-1 input (bf16)
  short*    Ab      = (short*)   alloc((size_t)NP_*2);   // gemm output (bf16)
  unsigned* Bagg    = (unsigned*)alloc((size_t)NP_*2);   // agg output (bf16 pairs)
  short*    Wt0     = (short*)   alloc(256*256*2);
  short*    Wt1     = (short*)   alloc(256*256*2);

  // edge structure + weights
  hipLaunchKernelGGL(k_init,  dim3(NT_/256),  dim3(256), 0, stream, degcnt, (const unsigned int*)mask, flag);
  hipLaunchKernelGGL(k_deg,   dim3(E16_/256), dim3(256), 0, stream, knn, mask, flag, degcnt);
  hipLaunchKernelGGL(k_scan,  dim3(1),        dim3(1024),0, stream, degcnt, rowptr, fillptr, dinv);
  hipLaunchKernelGGL(k_fill,  dim3(E16_/256), dim3(256), 0, stream, knn, mask, flag, fillptr, col);
  hipLaunchKernelGGL(k_cvt_w, dim3(128),      dim3(256), 0, stream, W0, W1, Wt0, Wt1);

  // layer 0
  hipLaunchKernelGGL(k_gemm_x, dim3(NT_/64),  dim3(512), 0, stream, x, Wt0, Ab);
  hipLaunchKernelGGL(k_agg,    dim3(NT_/8),   dim3(256), 0, stream, Ab, rowptr, col, dinv, b0, Bagg, partS, partQ);
  hipLaunchKernelGGL(k_stats,  dim3(1),       dim3(1024),0, stream, partS, partQ, stats);
  hipLaunchKernelGGL(k_norm_bf16, dim3(NP_/2048), dim3(256), 0, stream, Bagg, g0, be0, a0, stats, (unsigned*)Hb);

  // layer 1
  hipLaunchKernelGGL(k_gemm_h, dim3(NT_/64),  dim3(512), 0, stream, Hb, Wt1, Ab);
  hipLaunchKernelGGL(k_agg,    dim3(NT_/8),   dim3(256), 0, stream, Ab, rowptr, col, dinv, b1, Bagg, partS, partQ);
  hipLaunchKernelGGL(k_stats,  dim3(1),       dim3(1024),0, stream, partS, partQ, stats);
  hipLaunchKernelGGL(k_norm_f32,  dim3(NP_/2048), dim3(256), 0, stream, Bagg, g1, be1, a1, stats, out);
}

// Round 7
// 211.613 us; speedup vs baseline: 4.0515x; 1.0044x over previous
//
#include <hip/hip_runtime.h>
#include <hip/hip_bf16.h>
#include <stdint.h>

#define B_   8
#define N_   4096
#define K1_  17
#define D_   256
#define NT_  (B_*N_)          // 32768
#define E16_ (NT_*16)         // 524288
#define NP_  (NT_*D_)         // 8388608
#define EPS_ 1e-5f

typedef __attribute__((ext_vector_type(8))) short short8v;  // 8 bf16 (4 VGPR)
typedef __attribute__((ext_vector_type(4))) short short4v;
typedef __attribute__((ext_vector_type(4))) float f32x4;

// f32 -> bf16 RNE, pure C (verified rounds 1-3; m240: compiler codegen beats asm)
__device__ __forceinline__ unsigned short f2bfu(float f){
  unsigned u = __float_as_uint(f);
  unsigned r = (u + 0x7FFFu + ((u>>16)&1u)) >> 16;
  return (unsigned short)r;
}
__device__ __forceinline__ short f2bf(float f){ return (short)f2bfu(f); }
__device__ __forceinline__ unsigned pkbf(float lo, float hi){
  return (unsigned)f2bfu(lo) | ((unsigned)f2bfu(hi) << 16);
}
__device__ __forceinline__ float bf2f(short s){
  return __uint_as_float(((unsigned)(unsigned short)s) << 16);
}

// ---------------- edge-structure kernels ----------------

// zero degcnt (all blocks) + detect mask storage (block 0):
// flag: 0 = int32 {0,1}, 1 = float32 {0.f,1.f}, 2 = uint8/bool
__global__ __launch_bounds__(256) void k_init(int* __restrict__ degcnt,
                                              const unsigned int* __restrict__ mw,
                                              int* __restrict__ flag){
  int i = blockIdx.x*256 + threadIdx.x;
  degcnt[i] = 0;
  if (blockIdx.x == 0){
    __shared__ int s_int, s_f32;
    if (threadIdx.x==0){ s_int=1; s_f32=1; }
    __syncthreads();
    int bad_i=0, bad_f=0;
    #pragma unroll
    for (int j=0;j<4;j++){
      unsigned w = mw[threadIdx.x*4 + j];
      if (!(w==0u || w==1u))          bad_i=1;
      if (!(w==0u || w==0x3F800000u)) bad_f=1;
    }
    if (bad_i) atomicAnd(&s_int, 0);
    if (bad_f) atomicAnd(&s_f32, 0);
    __syncthreads();
    if (threadIdx.x==0) *flag = s_int ? 0 : (s_f32 ? 1 : 2);
  }
}

__device__ __forceinline__ bool mask_at(const void* maskp, int f, int idx){
  if (f==0) return ((const int*)maskp)[idx] != 0;
  if (f==1) return ((const float*)maskp)[idx] != 0.0f;
  return ((const unsigned char*)maskp)[idx] != 0;
}

__global__ void k_deg(const int* __restrict__ knn, const void* __restrict__ maskp,
                      const int* __restrict__ flag, int* __restrict__ degcnt){
  int f = *flag;
  int e = blockIdx.x*blockDim.x + threadIdx.x;
  if (e >= E16_) return;
  int node = e >> 4;            // b*N + n
  int k    = (e & 15) + 1;      // skip k=0
  int idx  = node*K1_ + k;
  if (mask_at(maskp, f, idx)){
    int b   = node >> 12;
    int dst = knn[idx] + (b<<12);
    atomicAdd(&degcnt[dst], 1);
  }
}

__global__ void k_scan(const int* __restrict__ degcnt, int* __restrict__ rowptr,
                       int* __restrict__ fillptr, float* __restrict__ dinv){
  __shared__ int sm[1024];
  int t = threadIdx.x;
  int base = t*32;
  int loc[32]; int tot = 0;
  #pragma unroll
  for (int i=0;i<32;i++){ loc[i] = degcnt[base+i]; tot += loc[i]; }
  sm[t] = tot; __syncthreads();
  for (int off=1; off<1024; off<<=1){
    int v = (t>=off) ? sm[t-off] : 0;
    __syncthreads();
    sm[t] += v;
    __syncthreads();
  }
  int run = sm[t] - tot;
  #pragma unroll
  for (int i=0;i<32;i++){
    int v = base+i;
    rowptr[v]  = run;
    fillptr[v] = run;
    dinv[v]    = rsqrtf((float)loc[i] + 1.0f);
    run += loc[i];
  }
  if (t==1023) rowptr[NT_] = run;
}

__global__ void k_fill(const int* __restrict__ knn, const void* __restrict__ maskp,
                       const int* __restrict__ flag, int* __restrict__ fillptr,
                       int* __restrict__ col){
  int f = *flag;
  int e = blockIdx.x*blockDim.x + threadIdx.x;
  if (e >= E16_) return;
  int node = e >> 4;
  int k    = (e & 15) + 1;
  int idx  = node*K1_ + k;
  if (mask_at(maskp, f, idx)){
    int b   = node >> 12;
    int dst = knn[idx] + (b<<12);
    int pos = atomicAdd(&fillptr[dst], 1);
    col[pos] = node;
  }
}

// ---------------- weight transpose (both layers, LDS-tiled) ----------------
// 128 blocks: even -> W0, odd -> W1; tile = 32x32. Wt[n][k] = bf16(W[k][n]).
__global__ __launch_bounds__(256) void k_cvt_w(const float* __restrict__ W0,
                                               const float* __restrict__ W1,
                                               short* __restrict__ Wt0,
                                               short* __restrict__ Wt1){
  const float* W  = (blockIdx.x & 1) ? W1  : W0;
  short*       Wt = (blockIdx.x & 1) ? Wt1 : Wt0;
  int tile = blockIdx.x >> 1;
  int ti = tile >> 3, tj = tile & 7;      // ti: k-tile, tj: n-tile
  __shared__ float sm[32][33];
  int r = threadIdx.x >> 5, c = threadIdx.x & 31;
  #pragma unroll
  for (int i=0;i<4;i++)
    sm[r + i*8][c] = W[(ti*32 + r + i*8)*256 + tj*32 + c];
  __syncthreads();
  #pragma unroll
  for (int i=0;i<4;i++){
    int rr = r + i*8;
    Wt[(size_t)(tj*32 + rr)*256 + ti*32 + c] = f2bf(sm[c][rr]);
  }
}

// ---------------- MFMA GEMM, B-resident-in-registers ----------------
// 512 thr = 8 waves; wave w owns col strips {2w,2w+1}. 64 rows per block.
// Round-6 post-mortem: with the row loop fully unrolled the compiler chose
// 48 VGPR and re-materialized the B loads per row-tile (44us, MfmaUtil 3.3%).
// Fix: '#pragma unroll 1' keeps the loop, LICM hoists the 16 B loads, and the
// no-op asm pin redefines each frag as an asm output so the allocator CANNOT
// re-load it from memory inside the loop.
// XCD swizzle: grid 512, XCD x gets 64 contiguous blocks = batch x.
// A frag: lane l holds row row0+(l&15), elems ks*32 + 8*(l>>4) + j
// B frag: lane l holds Wt[strip*16+(l&15)][ks*32 + 8*(l>>4) + j]
// D frag: lane l reg r -> D[row0 + 4*(l>>4)+r][strip*16 + (l&15)]

// layer 0: A read from x (f32, row stride 512), converted in-register
__global__ __launch_bounds__(512, 4) void k_gemm_x(const float* __restrict__ X,
                                                   const short* __restrict__ Wt,
                                                   short* __restrict__ Ab){
  int bid  = (int)(blockIdx.x & 7) * 64 + (int)(blockIdx.x >> 3);  // XCD swizzle
  int wave = threadIdx.x >> 6;
  int lane = threadIdx.x & 63;
  int lr   = lane & 15;
  int lk   = (lane >> 4) * 8;
  int s0   = wave*2, s1 = wave*2 + 1;

  short8v b0[8], b1[8];
  const short* w0p = Wt + (size_t)(s0*16 + lr)*256 + lk;
  const short* w1p = Wt + (size_t)(s1*16 + lr)*256 + lk;
  #pragma unroll
  for (int ks=0; ks<8; ks++){
    b0[ks] = *(const short8v*)(w0p + ks*32);
    b1[ks] = *(const short8v*)(w1p + ks*32);
  }
  #pragma unroll
  for (int ks=0; ks<8; ks++){
    asm volatile("" : "+v"(b0[ks]), "+v"(b1[ks]));   // pin in VGPRs
  }

  int rowB = bid*64;
  #pragma unroll 1
  for (int rt=0; rt<4; rt++){
    int row0 = rowB + rt*16;
    const float* aRow = X + (size_t)(row0 + lr)*512 + lk;
    f32x4 acc0 = (f32x4){0.f,0.f,0.f,0.f};
    f32x4 acc1 = (f32x4){0.f,0.f,0.f,0.f};
    #pragma unroll
    for (int ks=0; ks<8; ks++){
      f32x4 p0 = *(const f32x4*)(aRow + ks*32);
      f32x4 p1 = *(const f32x4*)(aRow + ks*32 + 4);
      union { unsigned u[4]; short8v v; } cv;
      cv.u[0] = pkbf(p0[0], p0[1]);
      cv.u[1] = pkbf(p0[2], p0[3]);
      cv.u[2] = pkbf(p1[0], p1[1]);
      cv.u[3] = pkbf(p1[2], p1[3]);
      acc0 = __builtin_amdgcn_mfma_f32_16x16x32_bf16(cv.v, b0[ks], acc0, 0, 0, 0);
      acc1 = __builtin_amdgcn_mfma_f32_16x16x32_bf16(cv.v, b1[ks], acc1, 0, 0, 0);
    }
    int mrow = row0 + (lane>>4)*4;
    #pragma unroll
    for (int r=0;r<4;r++){
      Ab[(size_t)(mrow + r)*256 + s0*16 + lr] = f2bf(acc0[r]);
      Ab[(size_t)(mrow + r)*256 + s1*16 + lr] = f2bf(acc1[r]);
    }
  }
}

// layer 1: A read from Hb (bf16, row stride 256)
__global__ __launch_bounds__(512, 4) void k_gemm_h(const short* __restrict__ Hb,
                                                   const short* __restrict__ Wt,
                                                   short* __restrict__ Ab){
  int bid  = (int)(blockIdx.x & 7) * 64 + (int)(blockIdx.x >> 3);  // XCD swizzle
  int wave = threadIdx.x >> 6;
  int lane = threadIdx.x & 63;
  int lr   = lane & 15;
  int lk   = (lane >> 4) * 8;
  int s0   = wave*2, s1 = wave*2 + 1;

  short8v b0[8], b1[8];
  const short* w0p = Wt + (size_t)(s0*16 + lr)*256 + lk;
  const short* w1p = Wt + (size_t)(s1*16 + lr)*256 + lk;
  #pragma unroll
  for (int ks=0; ks<8; ks++){
    b0[ks] = *(const short8v*)(w0p + ks*32);
    b1[ks] = *(const short8v*)(w1p + ks*32);
  }
  #pragma unroll
  for (int ks=0; ks<8; ks++){
    asm volatile("" : "+v"(b0[ks]), "+v"(b1[ks]));   // pin in VGPRs
  }

  int rowB = bid*64;
  #pragma unroll 1
  for (int rt=0; rt<4; rt++){
    int row0 = rowB + rt*16;
    const short* aRow = Hb + (size_t)(row0 + lr)*256 + lk;
    f32x4 acc0 = (f32x4){0.f,0.f,0.f,0.f};
    f32x4 acc1 = (f32x4){0.f,0.f,0.f,0.f};
    #pragma unroll
    for (int ks=0; ks<8; ks++){
      short8v a = *(const short8v*)(aRow + ks*32);
      acc0 = __builtin_amdgcn_mfma_f32_16x16x32_bf16(a, b0[ks], acc0, 0, 0, 0);
      acc1 = __builtin_amdgcn_mfma_f32_16x16x32_bf16(a, b1[ks], acc1, 0, 0, 0);
    }
    int mrow = row0 + (lane>>4)*4;
    #pragma unroll
    for (int r=0;r<4;r++){
      Ab[(size_t)(mrow + r)*256 + s0*16 + lr] = f2bf(acc0[r]);
      Ab[(size_t)(mrow + r)*256 + s1*16 + lr] = f2bf(acc1[r]);
    }
  }
}

// ---------------- aggregation: 32 lanes/node, XCD-swizzled, bf16 out ----------------
// 4096 blocks; swizzle so XCD x gets contiguous blocks = one batch (2MB, L2-fit).
// Per-block stats partials (8-node LDS reduce).
__global__ __launch_bounds__(256) void k_agg(const short* __restrict__ Ab,
    const int* __restrict__ rowptr, const int* __restrict__ col,
    const float* __restrict__ dinv, const float* __restrict__ bvec,
    unsigned* __restrict__ outU, float* __restrict__ partS, float* __restrict__ partQ){
  int bid  = (int)(blockIdx.x & 7) * 512 + (int)(blockIdx.x >> 3);  // XCD swizzle
  int node = bid*8 + (threadIdx.x >> 5);
  int sub  = threadIdx.x & 31;
  int c0   = sub*8;
  float dv = dinv[node];

  float acc[8];
  {
    short8v s = *(const short8v*)&Ab[(size_t)node*256 + c0];
    #pragma unroll
    for (int i=0;i<8;i++) acc[i] = dv * bf2f(s[i]);
  }
  int j0 = rowptr[node], j1 = rowptr[node+1];
  for (int j=j0;j<j1;j++){
    int s = col[j];
    float ds = dinv[s];
    short8v nb = *(const short8v*)&Ab[(size_t)s*256 + c0];
    #pragma unroll
    for (int i=0;i<8;i++) acc[i] += ds * bf2f(nb[i]);
  }
  float sum=0.f, sq=0.f;
  float o[8];
  #pragma unroll
  for (int i=0;i<8;i++){
    float v = dv*acc[i] + bvec[c0+i];
    o[i] = v;
    sum += v; sq += v*v;
  }
  uint4 ov;
  ov.x = pkbf(o[0],o[1]); ov.y = pkbf(o[2],o[3]);
  ov.z = pkbf(o[4],o[5]); ov.w = pkbf(o[6],o[7]);
  *(uint4*)&outU[(size_t)node*128 + sub*4] = ov;

  #pragma unroll
  for (int off=16; off>0; off>>=1){
    sum += __shfl_down(sum, off, 32);
    sq  += __shfl_down(sq,  off, 32);
  }
  __shared__ float ls1[8], ls2[8];
  if (sub==0){ ls1[threadIdx.x>>5]=sum; ls2[threadIdx.x>>5]=sq; }
  __syncthreads();
  if (threadIdx.x==0){
    float a=0.f, b=0.f;
    #pragma unroll
    for (int i=0;i<8;i++){ a+=ls1[i]; b+=ls2[i]; }
    partS[bid]=a; partQ[bid]=b;
  }
}

// ---------------- stats over 4096 per-block partials (double accum) ----------------
__global__ void k_stats(const float* __restrict__ partS, const float* __restrict__ partQ,
                        float* __restrict__ stats){
  __shared__ double s1[1024], s2[1024];
  int t = threadIdx.x;
  double a=0.0, b=0.0;
  for (int i=t; i<4096; i+=1024){ a += (double)partS[i]; b += (double)partQ[i]; }
  s1[t]=a; s2[t]=b; __syncthreads();
  for (int off=512; off>0; off>>=1){
    if (t<off){ s1[t]+=s1[t+off]; s2[t]+=s2[t+off]; }
    __syncthreads();
  }
  if (t==0){
    double mean = s1[0] / (double)NP_;
    double var  = s2[0] / (double)NP_ - mean*mean;
    var = var > 0.0 ? var : 0.0;
    stats[0] = (float)mean;
    stats[1] = (float)(1.0 / (sqrt(var) + (double)EPS_));
  }
}

// ---------------- norm + prelu (bf16 in; bf16 or f32 out), 8 elems/thread ----------------
__device__ __forceinline__ void unpack2(unsigned u, float& lo, float& hi){
  lo = __uint_as_float(u << 16);
  hi = __uint_as_float(u & 0xFFFF0000u);
}

__global__ __launch_bounds__(256) void k_norm_bf16(const unsigned* __restrict__ inU,
    const float* __restrict__ g, const float* __restrict__ be,
    const float* __restrict__ aP, const float* __restrict__ stats,
    unsigned* __restrict__ outU){
  float mean = stats[0], inv = stats[1], a = aP[0];
  int gid   = blockIdx.x*256 + threadIdx.x;
  int base8 = gid*8;
  int c0    = base8 & (D_-1);
  uint4 vin = *(const uint4*)&inU[gid*4];
  float4 g0 = *(const float4*)&g[c0],  g1 = *(const float4*)&g[c0+4];
  float4 e0 = *(const float4*)&be[c0], e1 = *(const float4*)&be[c0+4];
  float v[8];
  unpack2(vin.x, v[0], v[1]); unpack2(vin.y, v[2], v[3]);
  unpack2(vin.z, v[4], v[5]); unpack2(vin.w, v[6], v[7]);
  float gg[8] = {g0.x,g0.y,g0.z,g0.w,g1.x,g1.y,g1.z,g1.w};
  float eb[8] = {e0.x,e0.y,e0.z,e0.w,e1.x,e1.y,e1.z,e1.w};
  float o[8];
  #pragma unroll
  for (int i=0;i<8;i++){
    float t = gg[i]*((v[i]-mean)*inv) + eb[i];
    o[i] = t>=0.f ? t : a*t;
  }
  uint4 ov;
  ov.x = pkbf(o[0],o[1]); ov.y = pkbf(o[2],o[3]);
  ov.z = pkbf(o[4],o[5]); ov.w = pkbf(o[6],o[7]);
  *(uint4*)&outU[gid*4] = ov;
}

__global__ __launch_bounds__(256) void k_norm_f32(const unsigned* __restrict__ inU,
    const float* __restrict__ g, const float* __restrict__ be,
    const float* __restrict__ aP, const float* __restrict__ stats,
    float* __restrict__ out){
  float mean = stats[0], inv = stats[1], a = aP[0];
  int gid   = blockIdx.x*256 + threadIdx.x;
  int base8 = gid*8;
  int c0    = base8 & (D_-1);
  uint4 vin = *(const uint4*)&inU[gid*4];
  float4 g0 = *(const float4*)&g[c0],  g1 = *(const float4*)&g[c0+4];
  float4 e0 = *(const float4*)&be[c0], e1 = *(const float4*)&be[c0+4];
  float v[8];
  unpack2(vin.x, v[0], v[1]); unpack2(vin.y, v[2], v[3]);
  unpack2(vin.z, v[4], v[5]); unpack2(vin.w, v[6], v[7]);
  float gg[8] = {g0.x,g0.y,g0.z,g0.w,g1.x,g1.y,g1.z,g1.w};
  float eb[8] = {e0.x,e0.y,e0.z,e0.w,e1.x,e1.y,e1.z,e1.w};
  f32x4 o0, o1;
  #pragma unroll
  for (int i=0;i<8;i++){
    float t = gg[i]*((v[i]-mean)*inv) + eb[i];
    t = t>=0.f ? t : a*t;
    if (i<4) o0[i] = t; else o1[i-4] = t;
  }
  *(f32x4*)&out[base8]     = o0;
  *(f32x4*)&out[base8 + 4] = o1;
}

// ---------------- launch ----------------

extern "C" void kernel_launch(void* const* d_in, const int* in_sizes, int n_in,
                              void* d_out, int out_size, void* d_ws, size_t ws_size,
                              hipStream_t stream){
  const float* x    = (const float*)d_in[0];
  const int*   knn  = (const int*)  d_in[1];
  const void*  mask =               d_in[2];
  const float* W0   = (const float*)d_in[3];
  const float* b0   = (const float*)d_in[4];
  const float* g0   = (const float*)d_in[5];
  const float* be0  = (const float*)d_in[6];
  const float* a0   = (const float*)d_in[7];
  const float* W1   = (const float*)d_in[8];
  const float* b1   = (const float*)d_in[9];
  const float* g1   = (const float*)d_in[10];
  const float* be1  = (const float*)d_in[11];
  const float* a1   = (const float*)d_in[12];
  float* out = (float*)d_out;

  char* w = (char*)d_ws;
  size_t off = 0;
  auto alloc = [&](size_t bytes)->void*{
    void* p = w + off; off = (off + bytes + 255) & ~(size_t)255; return p;
  };
  int*      degcnt  = (int*)     alloc(NT_*4);
  int*      rowptr  = (int*)     alloc((NT_+1)*4);
  int*      fillptr = (int*)     alloc(NT_*4);
  int*      col     = (int*)     alloc(E16_*4);
  float*    dinv    = (float*)   alloc(NT_*4);
  float*    partS   = (float*)   alloc(4096*4);
  float*    partQ   = (float*)   alloc(4096*4);
  float*    stats   = (float*)   alloc(4*4);
  int*      flag    = (int*)     alloc(4);
  short*    Hb      = (short*)   alloc((size_t)NP_*2);   // layer-1 input (bf16)
  short*    Ab      = (short*)   alloc((size_t)NP_*2);   // gemm output (bf16)
  unsigned* Bagg    = (unsigned*)alloc((size_t)NP_*2);   // agg output (bf16 pairs)
  short*    Wt0     = (short*)   alloc(256*256*2);
  short*    Wt1     = (short*)   alloc(256*256*2);

  // edge structure + weights
  hipLaunchKernelGGL(k_init,  dim3(NT_/256),  dim3(256), 0, stream, degcnt, (const unsigned int*)mask, flag);
  hipLaunchKernelGGL(k_deg,   dim3(E16_/256), dim3(256), 0, stream, knn, mask, flag, degcnt);
  hipLaunchKernelGGL(k_scan,  dim3(1),        dim3(1024),0, stream, degcnt, rowptr, fillptr, dinv);
  hipLaunchKernelGGL(k_fill,  dim3(E16_/256), dim3(256), 0, stream, knn, mask, flag, fillptr, col);
  hipLaunchKernelGGL(k_cvt_w, dim3(128),      dim3(256), 0, stream, W0, W1, Wt0, Wt1);

  // layer 0
  hipLaunchKernelGGL(k_gemm_x, dim3(NT_/64),  dim3(512), 0, stream, x, Wt0, Ab);
  hipLaunchKernelGGL(k_agg,    dim3(NT_/8),   dim3(256), 0, stream, Ab, rowptr, col, dinv, b0, Bagg, partS, partQ);
  hipLaunchKernelGGL(k_stats,  dim3(1),       dim3(1024),0, stream, partS, partQ, stats);
  hipLaunchKernelGGL(k_norm_bf16, dim3(NP_/2048), dim3(256), 0, stream, Bagg, g0, be0, a0, stats, (unsigned*)Hb);

  // layer 1
  hipLaunchKernelGGL(k_gemm_h, dim3(NT_/64),  dim3(512), 0, stream, Hb, Wt1, Ab);
  hipLaunchKernelGGL(k_agg,    dim3(NT_/8),   dim3(256), 0, stream, Ab, rowptr, col, dinv, b1, Bagg, partS, partQ);
  hipLaunchKernelGGL(k_stats,  dim3(1),       dim3(1024),0, stream, partS, partQ, stats);
  hipLaunchKernelGGL(k_norm_f32,  dim3(NP_/2048), dim3(256), 0, stream, Bagg, g1, be1, a1, stats, out);
}